// Round 2
// baseline (192.844 us; speedup 1.0000x reference)
//
#include <hip/hip_runtime.h>
#include <stdint.h>

// Problem geometry (fixed by setup_inputs)
#define W_ 320
#define H_ 256
#define HW_ (W_ * H_)
#define NS_ 64
#define B_ 2
// Flat noise/output size N = B*NS*H*W; HALF = N/2 = NS*H*W (since B==2)
#define HALF_ (NS_ * HW_)   // 5,242,880

// ---------------- setup: proj = src_proj @ inv(gt_proj), store rot(9)+trans(3) ----------------

__device__ void inv4(const float* m, float* invOut) {
    float a[4][8];
    for (int i = 0; i < 4; i++) {
        for (int j = 0; j < 4; j++) {
            a[i][j] = m[i * 4 + j];
            a[i][j + 4] = (i == j) ? 1.0f : 0.0f;
        }
    }
    for (int c = 0; c < 4; c++) {
        int p = c;
        float best = fabsf(a[c][c]);
        for (int r = c + 1; r < 4; r++) {
            float v = fabsf(a[r][c]);
            if (v > best) { best = v; p = r; }
        }
        if (p != c) {
            for (int j = 0; j < 8; j++) { float tmp = a[c][j]; a[c][j] = a[p][j]; a[p][j] = tmp; }
        }
        float pinv = 1.0f / a[c][c];
        for (int j = 0; j < 8; j++) a[c][j] *= pinv;
        for (int r = 0; r < 4; r++) {
            if (r == c) continue;
            float f = a[r][c];
            for (int j = 0; j < 8; j++) a[r][j] -= f * a[c][j];
        }
    }
    for (int i = 0; i < 4; i++)
        for (int j = 0; j < 4; j++) invOut[i * 4 + j] = a[i][j + 4];
}

// pd layout: [b][src]{r00 r01 r02 r10 r11 r12 r20 r21 r22 t0 t1 t2}  (4 sets of 12 floats)
__global__ void setup_kernel(const float* __restrict__ lproj, const float* __restrict__ rproj,
                             const float* __restrict__ gproj, float* __restrict__ pd) {
    int tid = threadIdx.x;
    if (tid >= 4) return;
    int b = tid >> 1;
    int s = tid & 1;
    float inv[16];
    inv4(gproj + b * 16, inv);
    const float* sp = (s == 0 ? lproj : rproj) + b * 16;
    float* o = pd + tid * 12;
    for (int i = 0; i < 3; i++) {
        for (int j = 0; j < 3; j++) {
            float acc = 0.0f;
            for (int k = 0; k < 4; k++) acc += sp[i * 4 + k] * inv[k * 4 + j];
            o[i * 3 + j] = acc;
        }
    }
    for (int i = 0; i < 3; i++) {
        float acc = 0.0f;
        for (int k = 0; k < 4; k++) acc += sp[i * 4 + k] * inv[k * 4 + 3];
        o[9 + i] = acc;
    }
}

// ---------------- main kernel ----------------

__device__ __forceinline__ float u01(uint32_t b) {
    b = (b >> 9) | 0x3F800000u;
    return __uint_as_float(b) - 1.0f;
}

#define TF_ROUND(r) { x0 += x1; x1 = (x1 << (r)) | (x1 >> (32 - (r))); x1 ^= x0; }

// Threefry-2x32-20, key = (0, 1), partitionable-JAX finalizer: returns out0 ^ out1
// (jax _threefry_random_bits_partitionable: counter words (i>>32, i&0xffffffff),
//  bit_width==32 -> bits1 ^ bits2)
__device__ __forceinline__ uint32_t threefry20_xor(uint32_t c0, uint32_t c1) {
    const uint32_t ks0 = 0u, ks1 = 1u, ks2 = 0x1BD11BDAu ^ ks0 ^ ks1;
    uint32_t x0 = c0 + ks0;
    uint32_t x1 = c1 + ks1;
    TF_ROUND(13) TF_ROUND(15) TF_ROUND(26) TF_ROUND(6)
    x0 += ks1; x1 += ks2 + 1u;
    TF_ROUND(17) TF_ROUND(29) TF_ROUND(16) TF_ROUND(24)
    x0 += ks2; x1 += ks0 + 2u;
    TF_ROUND(13) TF_ROUND(15) TF_ROUND(26) TF_ROUND(6)
    x0 += ks0; x1 += ks1 + 3u;
    TF_ROUND(17) TF_ROUND(29) TF_ROUND(16) TF_ROUND(24)
    x0 += ks1; x1 += ks2 + 4u;
    TF_ROUND(13) TF_ROUND(15) TF_ROUND(26) TF_ROUND(6)
    x0 += ks2; x1 += ks0 + 5u;
    return x0 ^ x1;
}

__device__ __forceinline__ void corner(const float* __restrict__ img, float xc, float yc, float wgt,
                                       float& c0, float& c1, float& c2) {
    bool valid = (xc >= 0.0f) & (xc <= (float)(W_ - 1)) & (yc >= 0.0f) & (yc <= (float)(H_ - 1));
    float xcc = fminf(fmaxf(xc, 0.0f), (float)(W_ - 1));
    float ycc = fminf(fmaxf(yc, 0.0f), (float)(H_ - 1));
    int xi = (int)xcc;
    int yi = (int)ycc;
    int off = yi * W_ + xi;
    float wv = valid ? wgt : 0.0f;
    c0 += img[off] * wv;
    c1 += img[HW_ + off] * wv;
    c2 += img[2 * HW_ + off] * wv;
}

__device__ __forceinline__ void proj_sample(const float* __restrict__ img, const float* __restrict__ pd,
                                            float depth, float x, float y,
                                            float& c0, float& c1, float& c2) {
    float rx = pd[0] * x + pd[1] * y + pd[2];
    float ry = pd[3] * x + pd[4] * y + pd[5];
    float rz = pd[6] * x + pd[7] * y + pd[8];
    float px_ = rx * depth + pd[9];
    float py_ = ry * depth + pd[10];
    float pz_ = rz * depth + pd[11];
    bool neg = pz_ <= 0.001f;
    float z = neg ? 1.0f : pz_;
    float zi = __builtin_amdgcn_rcpf(z);
    float px = (neg ? (float)W_ : px_) * zi;
    float py = (neg ? (float)H_ : py_) * zi;

    float x0f = floorf(px), y0f = floorf(py);
    float wx1 = px - x0f, wy1 = py - y0f;
    float wx0 = 1.0f - wx1, wy0 = 1.0f - wy1;
    c0 = 0.0f; c1 = 0.0f; c2 = 0.0f;
    corner(img, x0f,        y0f,        wx0 * wy0, c0, c1, c2);
    corner(img, x0f + 1.0f, y0f,        wx1 * wy0, c0, c1, c2);
    corner(img, x0f,        y0f + 1.0f, wx0 * wy1, c0, c1, c2);
    corner(img, x0f + 1.0f, y0f + 1.0f, wx1 * wy1, c0, c1, c2);
}

__device__ __forceinline__ float sample_diff(const float* __restrict__ L, const float* __restrict__ R,
                                             const float* __restrict__ pdL, const float* __restrict__ pdR,
                                             float depth, float x, float y) {
    float l0, l1, l2, r0, r1, r2;
    proj_sample(L, pdL, depth, x, y, l0, l1, l2);
    proj_sample(R, pdR, depth, x, y, r0, r1, r2);
    return fabsf(r0 - l0) + fabsf(r1 - l1) + fabsf(r2 - l2);
}

__global__ __launch_bounds__(256) void volume_kernel(const float* __restrict__ limg,
                                                     const float* __restrict__ rimg,
                                                     const float* __restrict__ pd,
                                                     float* __restrict__ out) {
    int t = blockIdx.x * 256 + threadIdx.x;
    if (t >= HALF_) return;

    // Partitionable-JAX noise bits: flat index i -> threefry20(key=(0,1), (0, i)), out0^out1
    uint32_t bits0 = threefry20_xor(0u, (uint32_t)t);
    uint32_t bits1 = threefry20_xor(0u, (uint32_t)t + (uint32_t)HALF_);

    float n0 = u01(bits0);
    float n1 = u01(bits1);

    int w = t % W_;
    int rest = t / W_;
    int h = rest % H_;
    int d = rest / H_;

    float fd = (float)d;
    float s0 = n0 + fd;
    float s1 = n1 + fd;
    // depth = 1 / (inv_max + (s/64) * (inv_min - inv_max)); inv_min=0.1, inv_max=0.025
    float den0 = 0.025f + (s0 * 0.015625f) * 0.075f;
    float den1 = 0.025f + (s1 * 0.015625f) * 0.075f;
    float depth0 = __builtin_amdgcn_rcpf(den0);
    float depth1 = __builtin_amdgcn_rcpf(den1);

    float fx = (float)w;
    float fy = (float)h;

    // b = 0
    out[t] = sample_diff(limg, rimg, pd + 0, pd + 12, depth0, fx, fy);
    // b = 1
    out[t + HALF_] = sample_diff(limg + 3 * HW_, rimg + 3 * HW_, pd + 24, pd + 36, depth1, fx, fy);
}

extern "C" void kernel_launch(void* const* d_in, const int* in_sizes, int n_in,
                              void* d_out, int out_size, void* d_ws, size_t ws_size,
                              hipStream_t stream) {
    const float* limg  = (const float*)d_in[0];
    const float* rimg  = (const float*)d_in[1];
    const float* lproj = (const float*)d_in[2];
    const float* rproj = (const float*)d_in[3];
    const float* gproj = (const float*)d_in[4];
    float* out = (float*)d_out;
    float* pd  = (float*)d_ws;   // 48 floats

    setup_kernel<<<1, 64, 0, stream>>>(lproj, rproj, gproj, pd);
    volume_kernel<<<HALF_ / 256, 256, 0, stream>>>(limg, rimg, pd, out);
}

// Round 3
// 127.936 us; speedup vs baseline: 1.5074x; 1.5074x over previous
//
#include <hip/hip_runtime.h>
#include <stdint.h>

// Problem geometry (fixed by setup_inputs)
#define W_ 320
#define H_ 256
#define HW_ (W_ * H_)
#define NS_ 64
#define B_ 2
#define HALF_ (NS_ * HW_)   // 5,242,880 = NS*H*W (flat noise size / 2 since B==2)
#define D_PER 4

// ---------------- setup: proj = src_proj @ inv(gt_proj), store rot(9)+trans(3) ----------------

__device__ void inv4(const float* m, float* invOut) {
    float a[4][8];
    for (int i = 0; i < 4; i++) {
        for (int j = 0; j < 4; j++) {
            a[i][j] = m[i * 4 + j];
            a[i][j + 4] = (i == j) ? 1.0f : 0.0f;
        }
    }
    for (int c = 0; c < 4; c++) {
        int p = c;
        float best = fabsf(a[c][c]);
        for (int r = c + 1; r < 4; r++) {
            float v = fabsf(a[r][c]);
            if (v > best) { best = v; p = r; }
        }
        if (p != c) {
            for (int j = 0; j < 8; j++) { float tmp = a[c][j]; a[c][j] = a[p][j]; a[p][j] = tmp; }
        }
        float pinv = 1.0f / a[c][c];
        for (int j = 0; j < 8; j++) a[c][j] *= pinv;
        for (int r = 0; r < 4; r++) {
            if (r == c) continue;
            float f = a[r][c];
            for (int j = 0; j < 8; j++) a[r][j] -= f * a[c][j];
        }
    }
    for (int i = 0; i < 4; i++)
        for (int j = 0; j < 4; j++) invOut[i * 4 + j] = a[i][j + 4];
}

// pd layout: set = b*2+src (src: 0=L,1=R), 12 floats {r00..r22, t0,t1,t2}
__global__ void setup_kernel(const float* __restrict__ lproj, const float* __restrict__ rproj,
                             const float* __restrict__ gproj, float* __restrict__ pd) {
    int tid = threadIdx.x;
    if (tid >= 4) return;
    int b = tid >> 1;
    int s = tid & 1;
    float inv[16];
    inv4(gproj + b * 16, inv);
    const float* sp = (s == 0 ? lproj : rproj) + b * 16;
    float* o = pd + tid * 12;
    for (int i = 0; i < 3; i++) {
        for (int j = 0; j < 3; j++) {
            float acc = 0.0f;
            for (int k = 0; k < 4; k++) acc += sp[i * 4 + k] * inv[k * 4 + j];
            o[i * 3 + j] = acc;
        }
    }
    for (int i = 0; i < 3; i++) {
        float acc = 0.0f;
        for (int k = 0; k < 4; k++) acc += sp[i * 4 + k] * inv[k * 4 + 3];
        o[9 + i] = acc;
    }
}

// ---------------- channel-interleave pre-pass: [b][c][pix] -> float4[b][pix] ----------------
// ws4 layout: L at [b*HW_+pix], R at [B_*HW_ + b*HW_+pix]

__global__ __launch_bounds__(256) void interleave_kernel(const float* __restrict__ limg,
                                                         const float* __restrict__ rimg,
                                                         float4* __restrict__ out4) {
    int p = blockIdx.x * 256 + threadIdx.x;
    if (p >= B_ * HW_) return;
    int b = p / HW_;
    int pix = p - b * HW_;
    const float* Lb = limg + b * 3 * HW_;
    const float* Rb = rimg + b * 3 * HW_;
    out4[p] = make_float4(Lb[pix], Lb[HW_ + pix], Lb[2 * HW_ + pix], 0.0f);
    out4[B_ * HW_ + p] = make_float4(Rb[pix], Rb[HW_ + pix], Rb[2 * HW_ + pix], 0.0f);
}

// ---------------- RNG ----------------

__device__ __forceinline__ float u01(uint32_t b) {
    b = (b >> 9) | 0x3F800000u;
    return __uint_as_float(b) - 1.0f;
}

#define TF_ROUND(r) { x0 += x1; x1 = (x1 << (r)) | (x1 >> (32 - (r))); x1 ^= x0; }

// Threefry-2x32-20, key=(0,1), partitionable-JAX finalizer (out0 ^ out1)
__device__ __forceinline__ uint32_t threefry20_xor(uint32_t c0, uint32_t c1) {
    const uint32_t ks0 = 0u, ks1 = 1u, ks2 = 0x1BD11BDAu ^ ks0 ^ ks1;
    uint32_t x0 = c0 + ks0;
    uint32_t x1 = c1 + ks1;
    TF_ROUND(13) TF_ROUND(15) TF_ROUND(26) TF_ROUND(6)
    x0 += ks1; x1 += ks2 + 1u;
    TF_ROUND(17) TF_ROUND(29) TF_ROUND(16) TF_ROUND(24)
    x0 += ks2; x1 += ks0 + 2u;
    TF_ROUND(13) TF_ROUND(15) TF_ROUND(26) TF_ROUND(6)
    x0 += ks0; x1 += ks1 + 3u;
    TF_ROUND(17) TF_ROUND(29) TF_ROUND(16) TF_ROUND(24)
    x0 += ks1; x1 += ks2 + 4u;
    TF_ROUND(13) TF_ROUND(15) TF_ROUND(26) TF_ROUND(6)
    x0 += ks2; x1 += ks0 + 5u;
    return x0 ^ x1;
}

// ---------------- bilinear on interleaved float4 image ----------------

struct F3 { float x, y, z; };

__device__ __forceinline__ F3 bil4(const float4* __restrict__ img, float px, float py) {
    float x0f = floorf(px), y0f = floorf(py);
    float wx1 = px - x0f, wy1 = py - y0f;
    float wx0 = 1.0f - wx1, wy0 = 1.0f - wy1;
    int xi = (int)x0f, yi = (int)y0f;
    bool vx0 = (unsigned)xi < (unsigned)W_;
    bool vx1 = (unsigned)(xi + 1) < (unsigned)W_;
    bool vy0 = (unsigned)yi < (unsigned)H_;
    bool vy1 = (unsigned)(yi + 1) < (unsigned)H_;
    int cx0 = min(max(xi, 0), W_ - 1);
    int cx1 = min(max(xi + 1, 0), W_ - 1);
    int r0 = min(max(yi, 0), H_ - 1) * W_;
    int r1 = min(max(yi + 1, 0), H_ - 1) * W_;
    float w00 = (vx0 && vy0) ? wx0 * wy0 : 0.0f;
    float w10 = (vx1 && vy0) ? wx1 * wy0 : 0.0f;
    float w01 = (vx0 && vy1) ? wx0 * wy1 : 0.0f;
    float w11 = (vx1 && vy1) ? wx1 * wy1 : 0.0f;
    float4 p00 = img[r0 + cx0];
    float4 p10 = img[r0 + cx1];
    float4 p01 = img[r1 + cx0];
    float4 p11 = img[r1 + cx1];
    F3 o;
    o.x = p00.x * w00 + p10.x * w10 + p01.x * w01 + p11.x * w11;
    o.y = p00.y * w00 + p10.y * w10 + p01.y * w01 + p11.y * w11;
    o.z = p00.z * w00 + p10.z * w10 + p01.z * w01 + p11.z * w11;
    return o;
}

__device__ __forceinline__ F3 proj_bil(const float4* __restrict__ img,
                                       float rx, float ry, float rz,
                                       float tx, float ty, float tz, float depth) {
    float px_ = rx * depth + tx;
    float py_ = ry * depth + ty;
    float pz_ = rz * depth + tz;
    bool neg = pz_ <= 0.001f;
    float z = neg ? 1.0f : pz_;
    float zi = __builtin_amdgcn_rcpf(z);
    float px = (neg ? (float)W_ : px_) * zi;
    float py = (neg ? (float)H_ : py_) * zi;
    return bil4(img, px, py);
}

// ---------------- main kernel: D_PER depths per thread ----------------

__global__ __launch_bounds__(256) void volume4_kernel(const float4* __restrict__ img4,
                                                      const float* __restrict__ pd,
                                                      float* __restrict__ out) {
    int u = blockIdx.x * 256 + threadIdx.x;
    if (u >= HALF_ / D_PER) return;
    int pix = u % HW_;
    int dgrp = u / HW_;
    int w = pix % W_;
    int h = pix / W_;
    float fx = (float)w;
    float fy = (float)h;

    // per-(b,src) ray dir + trans; set = b*2+src
    float rx[4], ry[4], rz[4], tx[4], ty[4], tz[4];
#pragma unroll
    for (int s = 0; s < 4; s++) {
        const float* q = pd + s * 12;
        rx[s] = q[0] * fx + q[1] * fy + q[2];
        ry[s] = q[3] * fx + q[4] * fy + q[5];
        rz[s] = q[6] * fx + q[7] * fy + q[8];
        tx[s] = q[9]; ty[s] = q[10]; tz[s] = q[11];
    }

    const float4* L0 = img4;                  // b=0 left
    const float4* L1 = img4 + HW_;            // b=1 left
    const float4* R0 = img4 + 2 * HW_;        // b=0 right
    const float4* R1 = img4 + 3 * HW_;        // b=1 right

#pragma unroll
    for (int j = 0; j < D_PER; j++) {
        int d = dgrp * D_PER + j;
        int t = d * HW_ + pix;
        uint32_t bits0 = threefry20_xor(0u, (uint32_t)t);
        uint32_t bits1 = threefry20_xor(0u, (uint32_t)(t + HALF_));
        float fd = (float)d;
        float s0 = u01(bits0) + fd;
        float s1 = u01(bits1) + fd;
        float depth0 = __builtin_amdgcn_rcpf(0.025f + (s0 * 0.015625f) * 0.075f);
        float depth1 = __builtin_amdgcn_rcpf(0.025f + (s1 * 0.015625f) * 0.075f);

        F3 l0 = proj_bil(L0, rx[0], ry[0], rz[0], tx[0], ty[0], tz[0], depth0);
        F3 r0 = proj_bil(R0, rx[1], ry[1], rz[1], tx[1], ty[1], tz[1], depth0);
        F3 l1 = proj_bil(L1, rx[2], ry[2], rz[2], tx[2], ty[2], tz[2], depth1);
        F3 r1 = proj_bil(R1, rx[3], ry[3], rz[3], tx[3], ty[3], tz[3], depth1);

        out[t] = fabsf(r0.x - l0.x) + fabsf(r0.y - l0.y) + fabsf(r0.z - l0.z);
        out[t + HALF_] = fabsf(r1.x - l1.x) + fabsf(r1.y - l1.y) + fabsf(r1.z - l1.z);
    }
}

// ---------------- fallback (round-2 proven path, scalar loads) ----------------

__device__ __forceinline__ void corner(const float* __restrict__ img, float xc, float yc, float wgt,
                                       float& c0, float& c1, float& c2) {
    bool valid = (xc >= 0.0f) & (xc <= (float)(W_ - 1)) & (yc >= 0.0f) & (yc <= (float)(H_ - 1));
    float xcc = fminf(fmaxf(xc, 0.0f), (float)(W_ - 1));
    float ycc = fminf(fmaxf(yc, 0.0f), (float)(H_ - 1));
    int xi = (int)xcc;
    int yi = (int)ycc;
    int off = yi * W_ + xi;
    float wv = valid ? wgt : 0.0f;
    c0 += img[off] * wv;
    c1 += img[HW_ + off] * wv;
    c2 += img[2 * HW_ + off] * wv;
}

__device__ __forceinline__ void proj_sample_s(const float* __restrict__ img, const float* __restrict__ pd,
                                              float depth, float x, float y,
                                              float& c0, float& c1, float& c2) {
    float rx = pd[0] * x + pd[1] * y + pd[2];
    float ry = pd[3] * x + pd[4] * y + pd[5];
    float rz = pd[6] * x + pd[7] * y + pd[8];
    float px_ = rx * depth + pd[9];
    float py_ = ry * depth + pd[10];
    float pz_ = rz * depth + pd[11];
    bool neg = pz_ <= 0.001f;
    float z = neg ? 1.0f : pz_;
    float zi = __builtin_amdgcn_rcpf(z);
    float px = (neg ? (float)W_ : px_) * zi;
    float py = (neg ? (float)H_ : py_) * zi;
    float x0f = floorf(px), y0f = floorf(py);
    float wx1 = px - x0f, wy1 = py - y0f;
    float wx0 = 1.0f - wx1, wy0 = 1.0f - wy1;
    c0 = 0.0f; c1 = 0.0f; c2 = 0.0f;
    corner(img, x0f,        y0f,        wx0 * wy0, c0, c1, c2);
    corner(img, x0f + 1.0f, y0f,        wx1 * wy0, c0, c1, c2);
    corner(img, x0f,        y0f + 1.0f, wx0 * wy1, c0, c1, c2);
    corner(img, x0f + 1.0f, y0f + 1.0f, wx1 * wy1, c0, c1, c2);
}

__global__ __launch_bounds__(256) void volume_kernel(const float* __restrict__ limg,
                                                     const float* __restrict__ rimg,
                                                     const float* __restrict__ pd,
                                                     float* __restrict__ out) {
    int t = blockIdx.x * 256 + threadIdx.x;
    if (t >= HALF_) return;
    uint32_t bits0 = threefry20_xor(0u, (uint32_t)t);
    uint32_t bits1 = threefry20_xor(0u, (uint32_t)t + (uint32_t)HALF_);
    float n0 = u01(bits0);
    float n1 = u01(bits1);
    int w = t % W_;
    int rest = t / W_;
    int h = rest % H_;
    int d = rest / H_;
    float fd = (float)d;
    float den0 = 0.025f + ((n0 + fd) * 0.015625f) * 0.075f;
    float den1 = 0.025f + ((n1 + fd) * 0.015625f) * 0.075f;
    float depth0 = __builtin_amdgcn_rcpf(den0);
    float depth1 = __builtin_amdgcn_rcpf(den1);
    float fx = (float)w;
    float fy = (float)h;
    float l0, l1, l2, r0, r1, r2;
    proj_sample_s(limg, pd + 0, depth0, fx, fy, l0, l1, l2);
    proj_sample_s(rimg, pd + 12, depth0, fx, fy, r0, r1, r2);
    out[t] = fabsf(r0 - l0) + fabsf(r1 - l1) + fabsf(r2 - l2);
    proj_sample_s(limg + 3 * HW_, pd + 24, depth1, fx, fy, l0, l1, l2);
    proj_sample_s(rimg + 3 * HW_, pd + 36, depth1, fx, fy, r0, r1, r2);
    out[t + HALF_] = fabsf(r0 - l0) + fabsf(r1 - l1) + fabsf(r2 - l2);
}

extern "C" void kernel_launch(void* const* d_in, const int* in_sizes, int n_in,
                              void* d_out, int out_size, void* d_ws, size_t ws_size,
                              hipStream_t stream) {
    const float* limg  = (const float*)d_in[0];
    const float* rimg  = (const float*)d_in[1];
    const float* lproj = (const float*)d_in[2];
    const float* rproj = (const float*)d_in[3];
    const float* gproj = (const float*)d_in[4];
    float* out = (float*)d_out;
    float* pd  = (float*)d_ws;                                  // 48 floats
    float4* img4 = (float4*)((char*)d_ws + 256);                // 4*HW_ float4 = 5.24 MB

    const size_t need = 256 + (size_t)4 * HW_ * sizeof(float4);

    setup_kernel<<<1, 64, 0, stream>>>(lproj, rproj, gproj, pd);

    if (ws_size >= need) {
        interleave_kernel<<<(B_ * HW_ + 255) / 256, 256, 0, stream>>>(limg, rimg, img4);
        volume4_kernel<<<(HALF_ / D_PER + 255) / 256, 256, 0, stream>>>(img4, pd, out);
    } else {
        volume_kernel<<<HALF_ / 256, 256, 0, stream>>>(limg, rimg, pd, out);
    }
}

// Round 4
// 102.637 us; speedup vs baseline: 1.8789x; 1.2465x over previous
//
#include <hip/hip_runtime.h>
#include <stdint.h>

// Problem geometry (fixed by setup_inputs)
#define W_ 320
#define H_ 256
#define HW_ (W_ * H_)
#define NS_ 64
#define B_ 2
#define HALF_ (NS_ * HW_)   // 5,242,880 = NS*H*W (flat noise size / 2 since B==2)
#define D_PER 4

// ---------------- 4x4 inverse (Gauss-Jordan, partial pivot) ----------------

__device__ void inv4(const float* m, float* invOut) {
    float a[4][8];
    for (int i = 0; i < 4; i++) {
        for (int j = 0; j < 4; j++) {
            a[i][j] = m[i * 4 + j];
            a[i][j + 4] = (i == j) ? 1.0f : 0.0f;
        }
    }
    for (int c = 0; c < 4; c++) {
        int p = c;
        float best = fabsf(a[c][c]);
        for (int r = c + 1; r < 4; r++) {
            float v = fabsf(a[r][c]);
            if (v > best) { best = v; p = r; }
        }
        if (p != c) {
            for (int j = 0; j < 8; j++) { float tmp = a[c][j]; a[c][j] = a[p][j]; a[p][j] = tmp; }
        }
        float pinv = 1.0f / a[c][c];
        for (int j = 0; j < 8; j++) a[c][j] *= pinv;
        for (int r = 0; r < 4; r++) {
            if (r == c) continue;
            float f = a[r][c];
            for (int j = 0; j < 8; j++) a[r][j] -= f * a[c][j];
        }
    }
    for (int i = 0; i < 4; i++)
        for (int j = 0; j < 4; j++) invOut[i * 4 + j] = a[i][j + 4];
}

// ---------------- fused pre-pass ----------------
// pd layout: set = b*2+src (src 0=L,1=R): 12 floats {r00..r22, t0,t1,t2}.
// pd[48+set] = 1.0f if that set is a pure-x-shift warp (rot==I, ty==tz==0), else 0.
// img4 layout: L at [b*HW_+pix], R at [2*HW_ + b*HW_+pix], channels interleaved in float4.

__global__ __launch_bounds__(256) void prepass_kernel(const float* __restrict__ limg,
                                                      const float* __restrict__ rimg,
                                                      const float* __restrict__ lproj,
                                                      const float* __restrict__ rproj,
                                                      const float* __restrict__ gproj,
                                                      float* __restrict__ pd,
                                                      float4* __restrict__ out4) {
    int p = blockIdx.x * 256 + threadIdx.x;

    if (p < 4) {
        int b = p >> 1;
        int s = p & 1;
        float inv[16];
        inv4(gproj + b * 16, inv);
        const float* sp = (s == 0 ? lproj : rproj) + b * 16;
        float* o = pd + p * 12;
        for (int i = 0; i < 3; i++) {
            for (int j = 0; j < 3; j++) {
                float acc = 0.0f;
                for (int k = 0; k < 4; k++) acc += sp[i * 4 + k] * inv[k * 4 + j];
                o[i * 3 + j] = acc;
            }
        }
        for (int i = 0; i < 3; i++) {
            float acc = 0.0f;
            for (int k = 0; k < 4; k++) acc += sp[i * 4 + k] * inv[k * 4 + 3];
            o[9 + i] = acc;
        }
        // specialization check: rot ~= I, ty ~= 0, tz ~= 0 (t0 free)
        const float eps = 1e-4f;
        bool ok = fabsf(o[0] - 1.0f) < eps && fabsf(o[1]) < eps && fabsf(o[2]) < eps &&
                  fabsf(o[3]) < eps && fabsf(o[4] - 1.0f) < eps && fabsf(o[5]) < eps &&
                  fabsf(o[6]) < eps && fabsf(o[7]) < eps && fabsf(o[8] - 1.0f) < eps &&
                  fabsf(o[10]) < eps && fabsf(o[11]) < eps;
        pd[48 + p] = ok ? 1.0f : 0.0f;
    }

    if (p < B_ * HW_) {
        int b = p / HW_;
        int pix = p - b * HW_;
        const float* Lb = limg + b * 3 * HW_;
        const float* Rb = rimg + b * 3 * HW_;
        out4[p] = make_float4(Lb[pix], Lb[HW_ + pix], Lb[2 * HW_ + pix], 0.0f);
        out4[B_ * HW_ + p] = make_float4(Rb[pix], Rb[HW_ + pix], Rb[2 * HW_ + pix], 0.0f);
    }
}

// ---------------- RNG ----------------

__device__ __forceinline__ float u01(uint32_t b) {
    b = (b >> 9) | 0x3F800000u;
    return __uint_as_float(b) - 1.0f;
}

#define TF_ROUND(r) { x0 += x1; x1 = (x1 << (r)) | (x1 >> (32 - (r))); x1 ^= x0; }

// Threefry-2x32-20, key=(0,1), partitionable-JAX finalizer (out0 ^ out1)
__device__ __forceinline__ uint32_t threefry20_xor(uint32_t c0, uint32_t c1) {
    const uint32_t ks0 = 0u, ks1 = 1u, ks2 = 0x1BD11BDAu ^ ks0 ^ ks1;
    uint32_t x0 = c0 + ks0;
    uint32_t x1 = c1 + ks1;
    TF_ROUND(13) TF_ROUND(15) TF_ROUND(26) TF_ROUND(6)
    x0 += ks1; x1 += ks2 + 1u;
    TF_ROUND(17) TF_ROUND(29) TF_ROUND(16) TF_ROUND(24)
    x0 += ks2; x1 += ks0 + 2u;
    TF_ROUND(13) TF_ROUND(15) TF_ROUND(26) TF_ROUND(6)
    x0 += ks0; x1 += ks1 + 3u;
    TF_ROUND(17) TF_ROUND(29) TF_ROUND(16) TF_ROUND(24)
    x0 += ks1; x1 += ks2 + 4u;
    TF_ROUND(13) TF_ROUND(15) TF_ROUND(26) TF_ROUND(6)
    x0 += ks2; x1 += ks0 + 5u;
    return x0 ^ x1;
}

// ---------------- sampling helpers ----------------

struct F3 { float x, y, z; };

// 1-D horizontal lerp with zeros padding, row pointer already offset to y.
__device__ __forceinline__ F3 lerp1d(const float4* __restrict__ row, float px) {
    float x0f = floorf(px);
    float wx1 = px - x0f;
    float wx0 = 1.0f - wx1;
    int xi = (int)x0f;
    bool v0 = (unsigned)xi < (unsigned)W_;
    bool v1 = (unsigned)(xi + 1) < (unsigned)W_;
    int c0 = min(max(xi, 0), W_ - 1);
    int c1 = min(max(xi + 1, 0), W_ - 1);
    float w0 = v0 ? wx0 : 0.0f;
    float w1 = v1 ? wx1 : 0.0f;
    float4 p0 = row[c0];
    float4 p1 = row[c1];
    F3 o;
    o.x = p0.x * w0 + p1.x * w1;
    o.y = p0.y * w0 + p1.y * w1;
    o.z = p0.z * w0 + p1.z * w1;
    return o;
}

// full 2-D bilinear (general path)
__device__ __forceinline__ F3 bil4(const float4* __restrict__ img, float px, float py) {
    float x0f = floorf(px), y0f = floorf(py);
    float wx1 = px - x0f, wy1 = py - y0f;
    float wx0 = 1.0f - wx1, wy0 = 1.0f - wy1;
    int xi = (int)x0f, yi = (int)y0f;
    bool vx0 = (unsigned)xi < (unsigned)W_;
    bool vx1 = (unsigned)(xi + 1) < (unsigned)W_;
    bool vy0 = (unsigned)yi < (unsigned)H_;
    bool vy1 = (unsigned)(yi + 1) < (unsigned)H_;
    int cx0 = min(max(xi, 0), W_ - 1);
    int cx1 = min(max(xi + 1, 0), W_ - 1);
    int r0 = min(max(yi, 0), H_ - 1) * W_;
    int r1 = min(max(yi + 1, 0), H_ - 1) * W_;
    float w00 = (vx0 && vy0) ? wx0 * wy0 : 0.0f;
    float w10 = (vx1 && vy0) ? wx1 * wy0 : 0.0f;
    float w01 = (vx0 && vy1) ? wx0 * wy1 : 0.0f;
    float w11 = (vx1 && vy1) ? wx1 * wy1 : 0.0f;
    float4 p00 = img[r0 + cx0];
    float4 p10 = img[r0 + cx1];
    float4 p01 = img[r1 + cx0];
    float4 p11 = img[r1 + cx1];
    F3 o;
    o.x = p00.x * w00 + p10.x * w10 + p01.x * w01 + p11.x * w11;
    o.y = p00.y * w00 + p10.y * w10 + p01.y * w01 + p11.y * w11;
    o.z = p00.z * w00 + p10.z * w10 + p01.z * w01 + p11.z * w11;
    return o;
}

__device__ __forceinline__ F3 proj_bil(const float4* __restrict__ img,
                                       float rx, float ry, float rz,
                                       float tx, float ty, float tz, float depth) {
    float px_ = rx * depth + tx;
    float py_ = ry * depth + ty;
    float pz_ = rz * depth + tz;
    bool neg = pz_ <= 0.001f;
    float z = neg ? 1.0f : pz_;
    float zi = __builtin_amdgcn_rcpf(z);
    float px = (neg ? (float)W_ : px_) * zi;
    float py = (neg ? (float)H_ : py_) * zi;
    return bil4(img, px, py);
}

__device__ __forceinline__ float adiff3(F3 a, F3 b) {
    return fabsf(a.x - b.x) + fabsf(a.y - b.y) + fabsf(a.z - b.z);
}

// ---------------- main kernel ----------------

__global__ __launch_bounds__(256) void volume4_kernel(const float4* __restrict__ img4,
                                                      const float* __restrict__ pd,
                                                      float* __restrict__ out) {
    int u = blockIdx.x * 256 + threadIdx.x;
    if (u >= HALF_ / D_PER) return;
    int pix = u % HW_;
    int dgrp = u / HW_;
    int w = pix % W_;
    int h = pix / W_;
    float fx = (float)w;

    // wave-uniform specialization flag (all four warps must be pure-x-shift)
    bool fast = (pd[48] != 0.0f) & (pd[49] != 0.0f) & (pd[50] != 0.0f) & (pd[51] != 0.0f);

    const float4* L0 = img4;                  // b=0 left
    const float4* L1 = img4 + HW_;            // b=1 left
    const float4* R0 = img4 + 2 * HW_;        // b=0 right
    const float4* R1 = img4 + 3 * HW_;        // b=1 right

    if (fast) {
        // disparity-only warp: px = x + t0*den, py = y, depth never materialized
        float tl0 = pd[0 * 12 + 9];
        float tr0 = pd[1 * 12 + 9];
        float tl1 = pd[2 * 12 + 9];
        float tr1 = pd[3 * 12 + 9];
        const float4* rowL0 = L0 + h * W_;
        const float4* rowR0 = R0 + h * W_;
        const float4* rowL1 = L1 + h * W_;
        const float4* rowR1 = R1 + h * W_;

#pragma unroll
        for (int j = 0; j < D_PER; j++) {
            int d = dgrp * D_PER + j;
            int t = d * HW_ + pix;
            uint32_t bits0 = threefry20_xor(0u, (uint32_t)t);
            uint32_t bits1 = threefry20_xor(0u, (uint32_t)(t + HALF_));
            float fd = (float)d;
            // den = inv_max + (s/64)*(inv_min-inv_max); 1/depth == den
            float den0 = 0.025f + (u01(bits0) + fd) * 0.001171875f;
            float den1 = 0.025f + (u01(bits1) + fd) * 0.001171875f;

            F3 l0 = lerp1d(rowL0, fmaf(tl0, den0, fx));
            F3 r0 = lerp1d(rowR0, fmaf(tr0, den0, fx));
            F3 l1 = lerp1d(rowL1, fmaf(tl1, den1, fx));
            F3 r1 = lerp1d(rowR1, fmaf(tr1, den1, fx));

            out[t] = adiff3(r0, l0);
            out[t + HALF_] = adiff3(r1, l1);
        }
    } else {
        // general projective path (round-3 proven)
        float fy = (float)h;
        float rx[4], ry[4], rz[4], tx[4], ty[4], tz[4];
#pragma unroll
        for (int s = 0; s < 4; s++) {
            const float* q = pd + s * 12;
            rx[s] = q[0] * fx + q[1] * fy + q[2];
            ry[s] = q[3] * fx + q[4] * fy + q[5];
            rz[s] = q[6] * fx + q[7] * fy + q[8];
            tx[s] = q[9]; ty[s] = q[10]; tz[s] = q[11];
        }
#pragma unroll
        for (int j = 0; j < D_PER; j++) {
            int d = dgrp * D_PER + j;
            int t = d * HW_ + pix;
            uint32_t bits0 = threefry20_xor(0u, (uint32_t)t);
            uint32_t bits1 = threefry20_xor(0u, (uint32_t)(t + HALF_));
            float fd = (float)d;
            float s0 = u01(bits0) + fd;
            float s1 = u01(bits1) + fd;
            float depth0 = __builtin_amdgcn_rcpf(0.025f + (s0 * 0.015625f) * 0.075f);
            float depth1 = __builtin_amdgcn_rcpf(0.025f + (s1 * 0.015625f) * 0.075f);

            F3 l0 = proj_bil(L0, rx[0], ry[0], rz[0], tx[0], ty[0], tz[0], depth0);
            F3 r0 = proj_bil(R0, rx[1], ry[1], rz[1], tx[1], ty[1], tz[1], depth0);
            F3 l1 = proj_bil(L1, rx[2], ry[2], rz[2], tx[2], ty[2], tz[2], depth1);
            F3 r1 = proj_bil(R1, rx[3], ry[3], rz[3], tx[3], ty[3], tz[3], depth1);

            out[t] = adiff3(r0, l0);
            out[t + HALF_] = adiff3(r1, l1);
        }
    }
}

// ---------------- fallback (no-workspace path, round-2 proven) ----------------

__device__ __forceinline__ void corner(const float* __restrict__ img, float xc, float yc, float wgt,
                                       float& c0, float& c1, float& c2) {
    bool valid = (xc >= 0.0f) & (xc <= (float)(W_ - 1)) & (yc >= 0.0f) & (yc <= (float)(H_ - 1));
    float xcc = fminf(fmaxf(xc, 0.0f), (float)(W_ - 1));
    float ycc = fminf(fmaxf(yc, 0.0f), (float)(H_ - 1));
    int xi = (int)xcc;
    int yi = (int)ycc;
    int off = yi * W_ + xi;
    float wv = valid ? wgt : 0.0f;
    c0 += img[off] * wv;
    c1 += img[HW_ + off] * wv;
    c2 += img[2 * HW_ + off] * wv;
}

__device__ __forceinline__ void proj_sample_s(const float* __restrict__ img, const float* __restrict__ pd,
                                              float depth, float x, float y,
                                              float& c0, float& c1, float& c2) {
    float rx = pd[0] * x + pd[1] * y + pd[2];
    float ry = pd[3] * x + pd[4] * y + pd[5];
    float rz = pd[6] * x + pd[7] * y + pd[8];
    float px_ = rx * depth + pd[9];
    float py_ = ry * depth + pd[10];
    float pz_ = rz * depth + pd[11];
    bool neg = pz_ <= 0.001f;
    float z = neg ? 1.0f : pz_;
    float zi = __builtin_amdgcn_rcpf(z);
    float px = (neg ? (float)W_ : px_) * zi;
    float py = (neg ? (float)H_ : py_) * zi;
    float x0f = floorf(px), y0f = floorf(py);
    float wx1 = px - x0f, wy1 = py - y0f;
    float wx0 = 1.0f - wx1, wy0 = 1.0f - wy1;
    c0 = 0.0f; c1 = 0.0f; c2 = 0.0f;
    corner(img, x0f,        y0f,        wx0 * wy0, c0, c1, c2);
    corner(img, x0f + 1.0f, y0f,        wx1 * wy0, c0, c1, c2);
    corner(img, x0f,        y0f + 1.0f, wx0 * wy1, c0, c1, c2);
    corner(img, x0f + 1.0f, y0f + 1.0f, wx1 * wy1, c0, c1, c2);
}

__global__ __launch_bounds__(256) void volume_kernel(const float* __restrict__ limg,
                                                     const float* __restrict__ rimg,
                                                     const float* __restrict__ pd,
                                                     float* __restrict__ out) {
    int t = blockIdx.x * 256 + threadIdx.x;
    if (t >= HALF_) return;
    uint32_t bits0 = threefry20_xor(0u, (uint32_t)t);
    uint32_t bits1 = threefry20_xor(0u, (uint32_t)t + (uint32_t)HALF_);
    float n0 = u01(bits0);
    float n1 = u01(bits1);
    int w = t % W_;
    int rest = t / W_;
    int h = rest % H_;
    int d = rest / H_;
    float fd = (float)d;
    float depth0 = __builtin_amdgcn_rcpf(0.025f + ((n0 + fd) * 0.015625f) * 0.075f);
    float depth1 = __builtin_amdgcn_rcpf(0.025f + ((n1 + fd) * 0.015625f) * 0.075f);
    float fx = (float)w;
    float fy = (float)h;
    float l0, l1, l2, r0, r1, r2;
    proj_sample_s(limg, pd + 0, depth0, fx, fy, l0, l1, l2);
    proj_sample_s(rimg, pd + 12, depth0, fx, fy, r0, r1, r2);
    out[t] = fabsf(r0 - l0) + fabsf(r1 - l1) + fabsf(r2 - l2);
    proj_sample_s(limg + 3 * HW_, pd + 24, depth1, fx, fy, l0, l1, l2);
    proj_sample_s(rimg + 3 * HW_, pd + 36, depth1, fx, fy, r0, r1, r2);
    out[t + HALF_] = fabsf(r0 - l0) + fabsf(r1 - l1) + fabsf(r2 - l2);
}

__global__ void setup_only_kernel(const float* __restrict__ lproj, const float* __restrict__ rproj,
                                  const float* __restrict__ gproj, float* __restrict__ pd) {
    int tid = threadIdx.x;
    if (tid >= 4) return;
    int b = tid >> 1;
    int s = tid & 1;
    float inv[16];
    inv4(gproj + b * 16, inv);
    const float* sp = (s == 0 ? lproj : rproj) + b * 16;
    float* o = pd + tid * 12;
    for (int i = 0; i < 3; i++)
        for (int j = 0; j < 3; j++) {
            float acc = 0.0f;
            for (int k = 0; k < 4; k++) acc += sp[i * 4 + k] * inv[k * 4 + j];
            o[i * 3 + j] = acc;
        }
    for (int i = 0; i < 3; i++) {
        float acc = 0.0f;
        for (int k = 0; k < 4; k++) acc += sp[i * 4 + k] * inv[k * 4 + 3];
        o[9 + i] = acc;
    }
}

extern "C" void kernel_launch(void* const* d_in, const int* in_sizes, int n_in,
                              void* d_out, int out_size, void* d_ws, size_t ws_size,
                              hipStream_t stream) {
    const float* limg  = (const float*)d_in[0];
    const float* rimg  = (const float*)d_in[1];
    const float* lproj = (const float*)d_in[2];
    const float* rproj = (const float*)d_in[3];
    const float* gproj = (const float*)d_in[4];
    float* out = (float*)d_out;
    float* pd  = (float*)d_ws;                                  // 52 floats (+flags)
    float4* img4 = (float4*)((char*)d_ws + 256);                // 4*HW_ float4 = 5.24 MB

    const size_t need = 256 + (size_t)4 * HW_ * sizeof(float4);

    if (ws_size >= need) {
        prepass_kernel<<<(B_ * HW_ + 255) / 256, 256, 0, stream>>>(limg, rimg, lproj, rproj, gproj, pd, img4);
        volume4_kernel<<<(HALF_ / D_PER + 255) / 256, 256, 0, stream>>>(img4, pd, out);
    } else {
        setup_only_kernel<<<1, 64, 0, stream>>>(lproj, rproj, gproj, pd);
        volume_kernel<<<HALF_ / 256, 256, 0, stream>>>(limg, rimg, pd, out);
    }
}

// Round 5
// 101.241 us; speedup vs baseline: 1.9048x; 1.0138x over previous
//
#include <hip/hip_runtime.h>
#include <stdint.h>

// Problem geometry (fixed by setup_inputs)
#define W_ 320
#define H_ 256
#define HW_ (W_ * H_)
#define NS_ 64
#define B_ 2
#define HALF_ (NS_ * HW_)   // 5,242,880 = NS*H*W (flat noise size / 2 since B==2)
#define D_PER 4

// ---------------- 4x4 inverse (Gauss-Jordan, partial pivot) ----------------

__device__ void inv4(const float* m, float* invOut) {
    float a[4][8];
    for (int i = 0; i < 4; i++) {
        for (int j = 0; j < 4; j++) {
            a[i][j] = m[i * 4 + j];
            a[i][j + 4] = (i == j) ? 1.0f : 0.0f;
        }
    }
    for (int c = 0; c < 4; c++) {
        int p = c;
        float best = fabsf(a[c][c]);
        for (int r = c + 1; r < 4; r++) {
            float v = fabsf(a[r][c]);
            if (v > best) { best = v; p = r; }
        }
        if (p != c) {
            for (int j = 0; j < 8; j++) { float tmp = a[c][j]; a[c][j] = a[p][j]; a[p][j] = tmp; }
        }
        float pinv = 1.0f / a[c][c];
        for (int j = 0; j < 8; j++) a[c][j] *= pinv;
        for (int r = 0; r < 4; r++) {
            if (r == c) continue;
            float f = a[r][c];
            for (int j = 0; j < 8; j++) a[r][j] -= f * a[c][j];
        }
    }
    for (int i = 0; i < 4; i++)
        for (int j = 0; j < 4; j++) invOut[i * 4 + j] = a[i][j + 4];
}

// ---------------- fused pre-pass ----------------
// pd layout: set = b*2+src (src 0=L,1=R): 12 floats {r00..r22, t0,t1,t2}.
// pd[48+set] = 1.0f if pure-x-shift warp (rot==I, ty==tz==0, |t0|<160), else 0.
// img4 layout: L at [b*HW_+pix], R at [2*HW_ + b*HW_+pix], channels in float4.

__global__ __launch_bounds__(256) void prepass_kernel(const float* __restrict__ limg,
                                                      const float* __restrict__ rimg,
                                                      const float* __restrict__ lproj,
                                                      const float* __restrict__ rproj,
                                                      const float* __restrict__ gproj,
                                                      float* __restrict__ pd,
                                                      float4* __restrict__ out4) {
    int p = blockIdx.x * 256 + threadIdx.x;

    if (p < 4) {
        int b = p >> 1;
        int s = p & 1;
        float inv[16];
        inv4(gproj + b * 16, inv);
        const float* sp = (s == 0 ? lproj : rproj) + b * 16;
        float* o = pd + p * 12;
        for (int i = 0; i < 3; i++) {
            for (int j = 0; j < 3; j++) {
                float acc = 0.0f;
                for (int k = 0; k < 4; k++) acc += sp[i * 4 + k] * inv[k * 4 + j];
                o[i * 3 + j] = acc;
            }
        }
        for (int i = 0; i < 3; i++) {
            float acc = 0.0f;
            for (int k = 0; k < 4; k++) acc += sp[i * 4 + k] * inv[k * 4 + 3];
            o[9 + i] = acc;
        }
        // specialization check: rot ~= I, ty ~= 0, tz ~= 0, and t0 small enough
        // that per-thread disparity span (D_PER*0.0011719*|t0|) stays < 0.75 px
        const float eps = 1e-4f;
        bool ok = fabsf(o[0] - 1.0f) < eps && fabsf(o[1]) < eps && fabsf(o[2]) < eps &&
                  fabsf(o[3]) < eps && fabsf(o[4] - 1.0f) < eps && fabsf(o[5]) < eps &&
                  fabsf(o[6]) < eps && fabsf(o[7]) < eps && fabsf(o[8] - 1.0f) < eps &&
                  fabsf(o[10]) < eps && fabsf(o[11]) < eps &&
                  fabsf(o[9]) < 160.0f;
        pd[48 + p] = ok ? 1.0f : 0.0f;
    }

    if (p < B_ * HW_) {
        int b = p / HW_;
        int pix = p - b * HW_;
        const float* Lb = limg + b * 3 * HW_;
        const float* Rb = rimg + b * 3 * HW_;
        out4[p] = make_float4(Lb[pix], Lb[HW_ + pix], Lb[2 * HW_ + pix], 0.0f);
        out4[B_ * HW_ + p] = make_float4(Rb[pix], Rb[HW_ + pix], Rb[2 * HW_ + pix], 0.0f);
    }
}

// ---------------- RNG ----------------

__device__ __forceinline__ float u01(uint32_t b) {
    b = (b >> 9) | 0x3F800000u;
    return __uint_as_float(b) - 1.0f;
}

#define TF_ROUND(r) { x0 += x1; x1 = (x1 << (r)) | (x1 >> (32 - (r))); x1 ^= x0; }

// Threefry-2x32-20, key=(0,1), partitionable-JAX finalizer (out0 ^ out1)
__device__ __forceinline__ uint32_t threefry20_xor(uint32_t c0, uint32_t c1) {
    const uint32_t ks0 = 0u, ks1 = 1u, ks2 = 0x1BD11BDAu ^ ks0 ^ ks1;
    uint32_t x0 = c0 + ks0;
    uint32_t x1 = c1 + ks1;
    TF_ROUND(13) TF_ROUND(15) TF_ROUND(26) TF_ROUND(6)
    x0 += ks1; x1 += ks2 + 1u;
    TF_ROUND(17) TF_ROUND(29) TF_ROUND(16) TF_ROUND(24)
    x0 += ks2; x1 += ks0 + 2u;
    TF_ROUND(13) TF_ROUND(15) TF_ROUND(26) TF_ROUND(6)
    x0 += ks0; x1 += ks1 + 3u;
    TF_ROUND(17) TF_ROUND(29) TF_ROUND(16) TF_ROUND(24)
    x0 += ks1; x1 += ks2 + 4u;
    TF_ROUND(13) TF_ROUND(15) TF_ROUND(26) TF_ROUND(6)
    x0 += ks2; x1 += ks0 + 5u;
    return x0 ^ x1;
}

// ---------------- sampling helpers ----------------

struct F3 { float x, y, z; };

__device__ __forceinline__ float adiff3(F3 a, F3 b) {
    return fabsf(a.x - b.x) + fabsf(a.y - b.y) + fabsf(a.z - b.z);
}

// Fast path: all D_PER disparities for this row span < 1 px, so 3 taps
// (X, X+1, X+2) loaded once cover every j. OOB taps are zeroed at load
// (equivalent to zeros-padding since contribution = w * pixel).
__device__ __forceinline__ void row_sample4(const float4* __restrict__ row, float t0,
                                            const float den[D_PER], int w, F3 res[D_PER]) {
    float disp[D_PER];
#pragma unroll
    for (int j = 0; j < D_PER; j++) disp[j] = t0 * den[j];
    float m = fminf(fminf(disp[0], disp[1]), fminf(disp[2], disp[3]));
    float fm = floorf(m);
    int X = w + (int)fm;

    F3 q[3];
#pragma unroll
    for (int k = 0; k < 3; k++) {
        int xk = X + k;
        bool v = (unsigned)xk < (unsigned)W_;
        int c = min(max(xk, 0), W_ - 1);
        float4 pv = row[c];
        q[k].x = v ? pv.x : 0.0f;
        q[k].y = v ? pv.y : 0.0f;
        q[k].z = v ? pv.z : 0.0f;
    }

#pragma unroll
    for (int j = 0; j < D_PER; j++) {
        float fdj = floorf(disp[j]);
        float wx1 = disp[j] - fdj;
        float wx0 = 1.0f - wx1;
        bool hi = fdj > fm;     // tap offset 1 vs 0 (exact float compare: both floors)
        F3 p0, p1;
        p0.x = hi ? q[1].x : q[0].x;
        p0.y = hi ? q[1].y : q[0].y;
        p0.z = hi ? q[1].z : q[0].z;
        p1.x = hi ? q[2].x : q[1].x;
        p1.y = hi ? q[2].y : q[1].y;
        p1.z = hi ? q[2].z : q[1].z;
        res[j].x = p0.x * wx0 + p1.x * wx1;
        res[j].y = p0.y * wx0 + p1.y * wx1;
        res[j].z = p0.z * wx0 + p1.z * wx1;
    }
}

// full 2-D bilinear (general path)
__device__ __forceinline__ F3 bil4(const float4* __restrict__ img, float px, float py) {
    float x0f = floorf(px), y0f = floorf(py);
    float wx1 = px - x0f, wy1 = py - y0f;
    float wx0 = 1.0f - wx1, wy0 = 1.0f - wy1;
    int xi = (int)x0f, yi = (int)y0f;
    bool vx0 = (unsigned)xi < (unsigned)W_;
    bool vx1 = (unsigned)(xi + 1) < (unsigned)W_;
    bool vy0 = (unsigned)yi < (unsigned)H_;
    bool vy1 = (unsigned)(yi + 1) < (unsigned)H_;
    int cx0 = min(max(xi, 0), W_ - 1);
    int cx1 = min(max(xi + 1, 0), W_ - 1);
    int r0 = min(max(yi, 0), H_ - 1) * W_;
    int r1 = min(max(yi + 1, 0), H_ - 1) * W_;
    float w00 = (vx0 && vy0) ? wx0 * wy0 : 0.0f;
    float w10 = (vx1 && vy0) ? wx1 * wy0 : 0.0f;
    float w01 = (vx0 && vy1) ? wx0 * wy1 : 0.0f;
    float w11 = (vx1 && vy1) ? wx1 * wy1 : 0.0f;
    float4 p00 = img[r0 + cx0];
    float4 p10 = img[r0 + cx1];
    float4 p01 = img[r1 + cx0];
    float4 p11 = img[r1 + cx1];
    F3 o;
    o.x = p00.x * w00 + p10.x * w10 + p01.x * w01 + p11.x * w11;
    o.y = p00.y * w00 + p10.y * w10 + p01.y * w01 + p11.y * w11;
    o.z = p00.z * w00 + p10.z * w10 + p01.z * w01 + p11.z * w11;
    return o;
}

__device__ __forceinline__ F3 proj_bil(const float4* __restrict__ img,
                                       float rx, float ry, float rz,
                                       float tx, float ty, float tz, float depth) {
    float px_ = rx * depth + tx;
    float py_ = ry * depth + ty;
    float pz_ = rz * depth + tz;
    bool neg = pz_ <= 0.001f;
    float z = neg ? 1.0f : pz_;
    float zi = __builtin_amdgcn_rcpf(z);
    float px = (neg ? (float)W_ : px_) * zi;
    float py = (neg ? (float)H_ : py_) * zi;
    return bil4(img, px, py);
}

// ---------------- main kernel ----------------

__global__ __launch_bounds__(256) void volume4_kernel(const float4* __restrict__ img4,
                                                      const float* __restrict__ pd,
                                                      float* __restrict__ out) {
    int u = blockIdx.x * 256 + threadIdx.x;
    if (u >= HALF_ / D_PER) return;
    int pix = u % HW_;
    int dgrp = u / HW_;
    int w = pix % W_;
    int h = pix / W_;

    bool fast = (pd[48] != 0.0f) & (pd[49] != 0.0f) & (pd[50] != 0.0f) & (pd[51] != 0.0f);

    const float4* L0 = img4;                  // b=0 left
    const float4* L1 = img4 + HW_;            // b=1 left
    const float4* R0 = img4 + 2 * HW_;        // b=0 right
    const float4* R1 = img4 + 3 * HW_;        // b=1 right

    int tbase = dgrp * D_PER * HW_ + pix;

    if (fast) {
        float tl0 = pd[0 * 12 + 9];
        float tr0 = pd[1 * 12 + 9];
        float tl1 = pd[2 * 12 + 9];
        float tr1 = pd[3 * 12 + 9];
        const float4* rowL0 = L0 + h * W_;
        const float4* rowR0 = R0 + h * W_;
        const float4* rowL1 = L1 + h * W_;
        const float4* rowR1 = R1 + h * W_;

        float den0[D_PER], den1[D_PER];
#pragma unroll
        for (int j = 0; j < D_PER; j++) {
            int d = dgrp * D_PER + j;
            int t = tbase + j * HW_;
            uint32_t bits0 = threefry20_xor(0u, (uint32_t)t);
            uint32_t bits1 = threefry20_xor(0u, (uint32_t)(t + HALF_));
            float fd = (float)d;
            den0[j] = 0.025f + (u01(bits0) + fd) * 0.001171875f;
            den1[j] = 0.025f + (u01(bits1) + fd) * 0.001171875f;
        }

        F3 l[D_PER], r[D_PER];
        row_sample4(rowL0, tl0, den0, w, l);
        row_sample4(rowR0, tr0, den0, w, r);
#pragma unroll
        for (int j = 0; j < D_PER; j++)
            out[tbase + j * HW_] = adiff3(r[j], l[j]);

        row_sample4(rowL1, tl1, den1, w, l);
        row_sample4(rowR1, tr1, den1, w, r);
#pragma unroll
        for (int j = 0; j < D_PER; j++)
            out[tbase + j * HW_ + HALF_] = adiff3(r[j], l[j]);
    } else {
        // general projective path (round-3 proven)
        float fx = (float)w;
        float fy = (float)h;
        float rx[4], ry[4], rz[4], tx[4], ty[4], tz[4];
#pragma unroll
        for (int s = 0; s < 4; s++) {
            const float* q = pd + s * 12;
            rx[s] = q[0] * fx + q[1] * fy + q[2];
            ry[s] = q[3] * fx + q[4] * fy + q[5];
            rz[s] = q[6] * fx + q[7] * fy + q[8];
            tx[s] = q[9]; ty[s] = q[10]; tz[s] = q[11];
        }
#pragma unroll
        for (int j = 0; j < D_PER; j++) {
            int d = dgrp * D_PER + j;
            int t = tbase + j * HW_;
            uint32_t bits0 = threefry20_xor(0u, (uint32_t)t);
            uint32_t bits1 = threefry20_xor(0u, (uint32_t)(t + HALF_));
            float fd = (float)d;
            float s0 = u01(bits0) + fd;
            float s1 = u01(bits1) + fd;
            float depth0 = __builtin_amdgcn_rcpf(0.025f + (s0 * 0.015625f) * 0.075f);
            float depth1 = __builtin_amdgcn_rcpf(0.025f + (s1 * 0.015625f) * 0.075f);

            F3 l0 = proj_bil(L0, rx[0], ry[0], rz[0], tx[0], ty[0], tz[0], depth0);
            F3 r0 = proj_bil(R0, rx[1], ry[1], rz[1], tx[1], ty[1], tz[1], depth0);
            F3 l1 = proj_bil(L1, rx[2], ry[2], rz[2], tx[2], ty[2], tz[2], depth1);
            F3 r1 = proj_bil(R1, rx[3], ry[3], rz[3], tx[3], ty[3], tz[3], depth1);

            out[t] = adiff3(r0, l0);
            out[t + HALF_] = adiff3(r1, l1);
        }
    }
}

// ---------------- fallback (no-workspace path, round-2 proven) ----------------

__device__ __forceinline__ void corner(const float* __restrict__ img, float xc, float yc, float wgt,
                                       float& c0, float& c1, float& c2) {
    bool valid = (xc >= 0.0f) & (xc <= (float)(W_ - 1)) & (yc >= 0.0f) & (yc <= (float)(H_ - 1));
    float xcc = fminf(fmaxf(xc, 0.0f), (float)(W_ - 1));
    float ycc = fminf(fmaxf(yc, 0.0f), (float)(H_ - 1));
    int xi = (int)xcc;
    int yi = (int)ycc;
    int off = yi * W_ + xi;
    float wv = valid ? wgt : 0.0f;
    c0 += img[off] * wv;
    c1 += img[HW_ + off] * wv;
    c2 += img[2 * HW_ + off] * wv;
}

__device__ __forceinline__ void proj_sample_s(const float* __restrict__ img, const float* __restrict__ pd,
                                              float depth, float x, float y,
                                              float& c0, float& c1, float& c2) {
    float rx = pd[0] * x + pd[1] * y + pd[2];
    float ry = pd[3] * x + pd[4] * y + pd[5];
    float rz = pd[6] * x + pd[7] * y + pd[8];
    float px_ = rx * depth + pd[9];
    float py_ = ry * depth + pd[10];
    float pz_ = rz * depth + pd[11];
    bool neg = pz_ <= 0.001f;
    float z = neg ? 1.0f : pz_;
    float zi = __builtin_amdgcn_rcpf(z);
    float px = (neg ? (float)W_ : px_) * zi;
    float py = (neg ? (float)H_ : py_) * zi;
    float x0f = floorf(px), y0f = floorf(py);
    float wx1 = px - x0f, wy1 = py - y0f;
    float wx0 = 1.0f - wx1, wy0 = 1.0f - wy1;
    c0 = 0.0f; c1 = 0.0f; c2 = 0.0f;
    corner(img, x0f,        y0f,        wx0 * wy0, c0, c1, c2);
    corner(img, x0f + 1.0f, y0f,        wx1 * wy0, c0, c1, c2);
    corner(img, x0f,        y0f + 1.0f, wx0 * wy1, c0, c1, c2);
    corner(img, x0f + 1.0f, y0f + 1.0f, wx1 * wy1, c0, c1, c2);
}

__global__ __launch_bounds__(256) void volume_kernel(const float* __restrict__ limg,
                                                     const float* __restrict__ rimg,
                                                     const float* __restrict__ pd,
                                                     float* __restrict__ out) {
    int t = blockIdx.x * 256 + threadIdx.x;
    if (t >= HALF_) return;
    uint32_t bits0 = threefry20_xor(0u, (uint32_t)t);
    uint32_t bits1 = threefry20_xor(0u, (uint32_t)t + (uint32_t)HALF_);
    float n0 = u01(bits0);
    float n1 = u01(bits1);
    int w = t % W_;
    int rest = t / W_;
    int h = rest % H_;
    int d = rest / H_;
    float fd = (float)d;
    float depth0 = __builtin_amdgcn_rcpf(0.025f + ((n0 + fd) * 0.015625f) * 0.075f);
    float depth1 = __builtin_amdgcn_rcpf(0.025f + ((n1 + fd) * 0.015625f) * 0.075f);
    float fx = (float)w;
    float fy = (float)h;
    float l0, l1, l2, r0, r1, r2;
    proj_sample_s(limg, pd + 0, depth0, fx, fy, l0, l1, l2);
    proj_sample_s(rimg, pd + 12, depth0, fx, fy, r0, r1, r2);
    out[t] = fabsf(r0 - l0) + fabsf(r1 - l1) + fabsf(r2 - l2);
    proj_sample_s(limg + 3 * HW_, pd + 24, depth1, fx, fy, l0, l1, l2);
    proj_sample_s(rimg + 3 * HW_, pd + 36, depth1, fx, fy, r0, r1, r2);
    out[t + HALF_] = fabsf(r0 - l0) + fabsf(r1 - l1) + fabsf(r2 - l2);
}

__global__ void setup_only_kernel(const float* __restrict__ lproj, const float* __restrict__ rproj,
                                  const float* __restrict__ gproj, float* __restrict__ pd) {
    int tid = threadIdx.x;
    if (tid >= 4) return;
    int b = tid >> 1;
    int s = tid & 1;
    float inv[16];
    inv4(gproj + b * 16, inv);
    const float* sp = (s == 0 ? lproj : rproj) + b * 16;
    float* o = pd + tid * 12;
    for (int i = 0; i < 3; i++)
        for (int j = 0; j < 3; j++) {
            float acc = 0.0f;
            for (int k = 0; k < 4; k++) acc += sp[i * 4 + k] * inv[k * 4 + j];
            o[i * 3 + j] = acc;
        }
    for (int i = 0; i < 3; i++) {
        float acc = 0.0f;
        for (int k = 0; k < 4; k++) acc += sp[i * 4 + k] * inv[k * 4 + 3];
        o[9 + i] = acc;
    }
}

extern "C" void kernel_launch(void* const* d_in, const int* in_sizes, int n_in,
                              void* d_out, int out_size, void* d_ws, size_t ws_size,
                              hipStream_t stream) {
    const float* limg  = (const float*)d_in[0];
    const float* rimg  = (const float*)d_in[1];
    const float* lproj = (const float*)d_in[2];
    const float* rproj = (const float*)d_in[3];
    const float* gproj = (const float*)d_in[4];
    float* out = (float*)d_out;
    float* pd  = (float*)d_ws;                                  // 52 floats (+flags)
    float4* img4 = (float4*)((char*)d_ws + 256);                // 4*HW_ float4 = 5.24 MB

    const size_t need = 256 + (size_t)4 * HW_ * sizeof(float4);

    if (ws_size >= need) {
        prepass_kernel<<<(B_ * HW_ + 255) / 256, 256, 0, stream>>>(limg, rimg, lproj, rproj, gproj, pd, img4);
        volume4_kernel<<<(HALF_ / D_PER + 255) / 256, 256, 0, stream>>>(img4, pd, out);
    } else {
        setup_only_kernel<<<1, 64, 0, stream>>>(lproj, rproj, gproj, pd);
        volume_kernel<<<HALF_ / 256, 256, 0, stream>>>(limg, rimg, pd, out);
    }
}

// Round 6
// 99.905 us; speedup vs baseline: 1.9303x; 1.0134x over previous
//
#include <hip/hip_runtime.h>
#include <stdint.h>

// Problem geometry (fixed by setup_inputs)
#define W_ 320
#define H_ 256
#define HW_ (W_ * H_)
#define NS_ 64
#define B_ 2
#define HALF_ (NS_ * HW_)   // 5,242,880 = NS*H*W
#define D_PER 8
// Padded interleaved layout: per image-row, 16-px zero guard each side
#define PSTRIDE 352
#define POFF 16
#define PIMG (256 * PSTRIDE)   // 90112 float4 per image

// ---------------- 4x4 inverse (Gauss-Jordan, partial pivot) ----------------

__device__ void inv4(const float* m, float* invOut) {
    float a[4][8];
    for (int i = 0; i < 4; i++) {
        for (int j = 0; j < 4; j++) {
            a[i][j] = m[i * 4 + j];
            a[i][j + 4] = (i == j) ? 1.0f : 0.0f;
        }
    }
    for (int c = 0; c < 4; c++) {
        int p = c;
        float best = fabsf(a[c][c]);
        for (int r = c + 1; r < 4; r++) {
            float v = fabsf(a[r][c]);
            if (v > best) { best = v; p = r; }
        }
        if (p != c) {
            for (int j = 0; j < 8; j++) { float tmp = a[c][j]; a[c][j] = a[p][j]; a[p][j] = tmp; }
        }
        float pinv = 1.0f / a[c][c];
        for (int j = 0; j < 8; j++) a[c][j] *= pinv;
        for (int r = 0; r < 4; r++) {
            if (r == c) continue;
            float f = a[r][c];
            for (int j = 0; j < 8; j++) a[r][j] -= f * a[c][j];
        }
    }
    for (int i = 0; i < 4; i++)
        for (int j = 0; j < 4; j++) invOut[i * 4 + j] = a[i][j + 4];
}

// ---------------- fused pre-pass ----------------
// pd: set = b*2+src (src 0=L,1=R): 12 floats {r00..r22,t0,t1,t2}; pd[48+set]=fast flag.
// img4 (padded): img 0=L/b0, 1=L/b1, 2=R/b0, 3=R/b1; element (img,h,xp) at
// img*PIMG + h*PSTRIDE + xp, real x = xp-POFF, zeros outside [0,W).

__global__ __launch_bounds__(256) void prepass_kernel(const float* __restrict__ limg,
                                                      const float* __restrict__ rimg,
                                                      const float* __restrict__ lproj,
                                                      const float* __restrict__ rproj,
                                                      const float* __restrict__ gproj,
                                                      float* __restrict__ pd,
                                                      float4* __restrict__ out4) {
    int p = blockIdx.x * 256 + threadIdx.x;

    if (p < 4) {
        int b = p >> 1;
        int s = p & 1;
        float inv[16];
        inv4(gproj + b * 16, inv);
        const float* sp = (s == 0 ? lproj : rproj) + b * 16;
        float* o = pd + p * 12;
        for (int i = 0; i < 3; i++) {
            for (int j = 0; j < 3; j++) {
                float acc = 0.0f;
                for (int k = 0; k < 4; k++) acc += sp[i * 4 + k] * inv[k * 4 + j];
                o[i * 3 + j] = acc;
            }
        }
        for (int i = 0; i < 3; i++) {
            float acc = 0.0f;
            for (int k = 0; k < 4; k++) acc += sp[i * 4 + k] * inv[k * 4 + 3];
            o[9 + i] = acc;
        }
        // fast iff pure x-shift and |t0| small enough that (a) 8-depth disparity
        // span < 1 px (|t0|*8*0.0011719 < 1) and (b) |disp| <= |t0|*0.1 < POFF-1
        const float eps = 1e-4f;
        bool ok = fabsf(o[0] - 1.0f) < eps && fabsf(o[1]) < eps && fabsf(o[2]) < eps &&
                  fabsf(o[3]) < eps && fabsf(o[4] - 1.0f) < eps && fabsf(o[5]) < eps &&
                  fabsf(o[6]) < eps && fabsf(o[7]) < eps && fabsf(o[8] - 1.0f) < eps &&
                  fabsf(o[10]) < eps && fabsf(o[11]) < eps &&
                  fabsf(o[9]) < 100.0f;
        pd[48 + p] = ok ? 1.0f : 0.0f;
    }

    if (p < 4 * PIMG) {
        int img = p / PIMG;
        int rem = p - img * PIMG;
        int h = rem / PSTRIDE;
        int xp = rem - h * PSTRIDE;
        int x = xp - POFF;
        bool v = (unsigned)x < (unsigned)W_;
        int b = img & 1;
        const float* src = (img < 2 ? limg : rimg) + b * 3 * HW_;
        int pix = h * W_ + min(max(x, 0), W_ - 1);
        float4 val;
        val.x = v ? src[pix] : 0.0f;
        val.y = v ? src[HW_ + pix] : 0.0f;
        val.z = v ? src[2 * HW_ + pix] : 0.0f;
        val.w = 0.0f;
        out4[p] = val;
    }
}

// ---------------- RNG ----------------

__device__ __forceinline__ float u01(uint32_t b) {
    b = (b >> 9) | 0x3F800000u;
    return __uint_as_float(b) - 1.0f;
}

#define TF_ROUND(r) { x0 += x1; x1 = (x1 << (r)) | (x1 >> (32 - (r))); x1 ^= x0; }

// Threefry-2x32-20, key=(0,1), partitionable-JAX finalizer (out0 ^ out1)
__device__ __forceinline__ uint32_t threefry20_xor(uint32_t c0, uint32_t c1) {
    const uint32_t ks0 = 0u, ks1 = 1u, ks2 = 0x1BD11BDAu ^ ks0 ^ ks1;
    uint32_t x0 = c0 + ks0;
    uint32_t x1 = c1 + ks1;
    TF_ROUND(13) TF_ROUND(15) TF_ROUND(26) TF_ROUND(6)
    x0 += ks1; x1 += ks2 + 1u;
    TF_ROUND(17) TF_ROUND(29) TF_ROUND(16) TF_ROUND(24)
    x0 += ks2; x1 += ks0 + 2u;
    TF_ROUND(13) TF_ROUND(15) TF_ROUND(26) TF_ROUND(6)
    x0 += ks0; x1 += ks1 + 3u;
    TF_ROUND(17) TF_ROUND(29) TF_ROUND(16) TF_ROUND(24)
    x0 += ks1; x1 += ks2 + 4u;
    TF_ROUND(13) TF_ROUND(15) TF_ROUND(26) TF_ROUND(6)
    x0 += ks2; x1 += ks0 + 5u;
    return x0 ^ x1;
}

__device__ __forceinline__ float noise_den(uint32_t t, float fd) {
    return 0.025f + (u01(threefry20_xor(0u, t)) + fd) * 0.001171875f;
}

// ---------------- helpers ----------------

struct F3 { float x, y, z; };

__device__ __forceinline__ float adiff3(F3 a, F3 b) {
    return fabsf(a.x - b.x) + fabsf(a.y - b.y) + fabsf(a.z - b.z);
}

// hat-weight 3-tap lerp: x in [0,2), taps at offsets 0,1,2 from floor base
__device__ __forceinline__ F3 hat3(float4 q0, float4 q1, float4 q2, float x) {
    float t = x - 1.0f;
    float w0 = fmaxf(0.0f, 1.0f - x);
    float w1 = 1.0f - fabsf(t);
    float w2 = fmaxf(0.0f, t);
    F3 o;
    o.x = q0.x * w0 + q1.x * w1 + q2.x * w2;
    o.y = q0.y * w0 + q1.y * w1 + q2.y * w2;
    o.z = q0.z * w0 + q1.z * w1 + q2.z * w2;
    return o;
}

// full 2-D bilinear on padded layout (general path)
__device__ __forceinline__ F3 bil4(const float4* __restrict__ img, float px, float py) {
    float x0f = floorf(px), y0f = floorf(py);
    float wx1 = px - x0f, wy1 = py - y0f;
    float wx0 = 1.0f - wx1, wy0 = 1.0f - wy1;
    int xi = (int)x0f, yi = (int)y0f;
    bool vx0 = (unsigned)xi < (unsigned)W_;
    bool vx1 = (unsigned)(xi + 1) < (unsigned)W_;
    bool vy0 = (unsigned)yi < (unsigned)H_;
    bool vy1 = (unsigned)(yi + 1) < (unsigned)H_;
    int cx0 = min(max(xi, 0), W_ - 1) + POFF;
    int cx1 = min(max(xi + 1, 0), W_ - 1) + POFF;
    int r0 = min(max(yi, 0), H_ - 1) * PSTRIDE;
    int r1 = min(max(yi + 1, 0), H_ - 1) * PSTRIDE;
    float w00 = (vx0 && vy0) ? wx0 * wy0 : 0.0f;
    float w10 = (vx1 && vy0) ? wx1 * wy0 : 0.0f;
    float w01 = (vx0 && vy1) ? wx0 * wy1 : 0.0f;
    float w11 = (vx1 && vy1) ? wx1 * wy1 : 0.0f;
    float4 p00 = img[r0 + cx0];
    float4 p10 = img[r0 + cx1];
    float4 p01 = img[r1 + cx0];
    float4 p11 = img[r1 + cx1];
    F3 o;
    o.x = p00.x * w00 + p10.x * w10 + p01.x * w01 + p11.x * w11;
    o.y = p00.y * w00 + p10.y * w10 + p01.y * w01 + p11.y * w11;
    o.z = p00.z * w00 + p10.z * w10 + p01.z * w01 + p11.z * w11;
    return o;
}

__device__ __forceinline__ F3 proj_bil(const float4* __restrict__ img,
                                       float rx, float ry, float rz,
                                       float tx, float ty, float tz, float depth) {
    float px_ = rx * depth + tx;
    float py_ = ry * depth + ty;
    float pz_ = rz * depth + tz;
    bool neg = pz_ <= 0.001f;
    float z = neg ? 1.0f : pz_;
    float zi = __builtin_amdgcn_rcpf(z);
    float px = (neg ? (float)W_ : px_) * zi;
    float py = (neg ? (float)H_ : py_) * zi;
    return bil4(img, px, py);
}

// ---------------- main kernel: 8 depths per thread ----------------

__global__ __launch_bounds__(256) void volume8_kernel(const float4* __restrict__ img4,
                                                      const float* __restrict__ pd,
                                                      float* __restrict__ out) {
    int u = blockIdx.x * 256 + threadIdx.x;
    if (u >= HALF_ / D_PER) return;
    int pix = u % HW_;
    int dgrp = u / HW_;
    int w = pix % W_;
    int h = pix / W_;
    int d0 = dgrp * D_PER;
    int tbase = d0 * HW_ + pix;

    bool fast = (pd[48] != 0.0f) & (pd[49] != 0.0f) & (pd[50] != 0.0f) & (pd[51] != 0.0f);

    // padded row bases, already offset to pixel w (taps indexed relative)
    const float4* rowL0 = img4 + 0 * PIMG + h * PSTRIDE + POFF + w;
    const float4* rowL1 = img4 + 1 * PIMG + h * PSTRIDE + POFF + w;
    const float4* rowR0 = img4 + 2 * PIMG + h * PSTRIDE + POFF + w;
    const float4* rowR1 = img4 + 3 * PIMG + h * PSTRIDE + POFF + w;

    if (fast) {
        float tl0 = pd[0 * 12 + 9];
        float tr0 = pd[1 * 12 + 9];
        float tl1 = pd[2 * 12 + 9];
        float tr1 = pd[3 * 12 + 9];

        float den0[D_PER], den1[D_PER];
        // Stage A: only the extreme-j noise needed to place taps (den sorted in j)
        den0[0]         = noise_den((uint32_t)tbase,                          (float)d0);
        den0[D_PER - 1] = noise_den((uint32_t)(tbase + (D_PER - 1) * HW_),    (float)(d0 + D_PER - 1));
        den1[0]         = noise_den((uint32_t)(tbase + HALF_),                (float)d0);
        den1[D_PER - 1] = noise_den((uint32_t)(tbase + (D_PER - 1) * HW_ + HALF_), (float)(d0 + D_PER - 1));

        // Stage B: tap bases + issue all 12 loads
        float dmL0 = (tl0 >= 0.0f) ? den0[0] : den0[D_PER - 1];
        float dmR0 = (tr0 >= 0.0f) ? den0[0] : den0[D_PER - 1];
        float dmL1 = (tl1 >= 0.0f) ? den1[0] : den1[D_PER - 1];
        float dmR1 = (tr1 >= 0.0f) ? den1[0] : den1[D_PER - 1];
        float fmL0 = floorf(tl0 * dmL0);
        float fmR0 = floorf(tr0 * dmR0);
        float fmL1 = floorf(tl1 * dmL1);
        float fmR1 = floorf(tr1 * dmR1);
        const float4* tL0 = rowL0 + (int)fmL0;
        const float4* tR0 = rowR0 + (int)fmR0;
        const float4* tL1 = rowL1 + (int)fmL1;
        const float4* tR1 = rowR1 + (int)fmR1;
        float4 qL0a = tL0[0], qL0b = tL0[1], qL0c = tL0[2];
        float4 qR0a = tR0[0], qR0b = tR0[1], qR0c = tR0[2];
        float4 qL1a = tL1[0], qL1b = tL1[1], qL1c = tL1[2];
        float4 qR1a = tR1[0], qR1b = tR1[1], qR1c = tR1[2];

        // Stage C: remaining threefry in the load shadow
#pragma unroll
        for (int j = 1; j < D_PER - 1; j++) {
            den0[j] = noise_den((uint32_t)(tbase + j * HW_),         (float)(d0 + j));
            den1[j] = noise_den((uint32_t)(tbase + j * HW_ + HALF_), (float)(d0 + j));
        }

        // Stage D: lerp + diff + store
#pragma unroll
        for (int j = 0; j < D_PER; j++) {
            F3 l0 = hat3(qL0a, qL0b, qL0c, tl0 * den0[j] - fmL0);
            F3 r0 = hat3(qR0a, qR0b, qR0c, tr0 * den0[j] - fmR0);
            out[tbase + j * HW_] = adiff3(r0, l0);
            F3 l1 = hat3(qL1a, qL1b, qL1c, tl1 * den1[j] - fmL1);
            F3 r1 = hat3(qR1a, qR1b, qR1c, tr1 * den1[j] - fmR1);
            out[tbase + j * HW_ + HALF_] = adiff3(r1, l1);
        }
    } else {
        // general projective path
        float fx = (float)w;
        float fy = (float)h;
        float rx[4], ry[4], rz[4], tx[4], ty[4], tz[4];
#pragma unroll
        for (int s = 0; s < 4; s++) {
            const float* q = pd + s * 12;
            rx[s] = q[0] * fx + q[1] * fy + q[2];
            ry[s] = q[3] * fx + q[4] * fy + q[5];
            rz[s] = q[6] * fx + q[7] * fy + q[8];
            tx[s] = q[9]; ty[s] = q[10]; tz[s] = q[11];
        }
        const float4* I0 = img4;
        const float4* I1 = img4 + PIMG;
        const float4* I2 = img4 + 2 * PIMG;
        const float4* I3 = img4 + 3 * PIMG;
#pragma unroll
        for (int j = 0; j < D_PER; j++) {
            int d = d0 + j;
            int t = tbase + j * HW_;
            uint32_t bits0 = threefry20_xor(0u, (uint32_t)t);
            uint32_t bits1 = threefry20_xor(0u, (uint32_t)(t + HALF_));
            float fd = (float)d;
            float depth0 = __builtin_amdgcn_rcpf(0.025f + (u01(bits0) + fd) * 0.001171875f);
            float depth1 = __builtin_amdgcn_rcpf(0.025f + (u01(bits1) + fd) * 0.001171875f);

            F3 l0 = proj_bil(I0, rx[0], ry[0], rz[0], tx[0], ty[0], tz[0], depth0);
            F3 r0 = proj_bil(I2, rx[1], ry[1], rz[1], tx[1], ty[1], tz[1], depth0);
            F3 l1 = proj_bil(I1, rx[2], ry[2], rz[2], tx[2], ty[2], tz[2], depth1);
            F3 r1 = proj_bil(I3, rx[3], ry[3], rz[3], tx[3], ty[3], tz[3], depth1);

            out[t] = adiff3(r0, l0);
            out[t + HALF_] = adiff3(r1, l1);
        }
    }
}

// ---------------- fallback (no-workspace path, round-2 proven) ----------------

__device__ __forceinline__ void corner(const float* __restrict__ img, float xc, float yc, float wgt,
                                       float& c0, float& c1, float& c2) {
    bool valid = (xc >= 0.0f) & (xc <= (float)(W_ - 1)) & (yc >= 0.0f) & (yc <= (float)(H_ - 1));
    float xcc = fminf(fmaxf(xc, 0.0f), (float)(W_ - 1));
    float ycc = fminf(fmaxf(yc, 0.0f), (float)(H_ - 1));
    int xi = (int)xcc;
    int yi = (int)ycc;
    int off = yi * W_ + xi;
    float wv = valid ? wgt : 0.0f;
    c0 += img[off] * wv;
    c1 += img[HW_ + off] * wv;
    c2 += img[2 * HW_ + off] * wv;
}

__device__ __forceinline__ void proj_sample_s(const float* __restrict__ img, const float* __restrict__ pd,
                                              float depth, float x, float y,
                                              float& c0, float& c1, float& c2) {
    float rx = pd[0] * x + pd[1] * y + pd[2];
    float ry = pd[3] * x + pd[4] * y + pd[5];
    float rz = pd[6] * x + pd[7] * y + pd[8];
    float px_ = rx * depth + pd[9];
    float py_ = ry * depth + pd[10];
    float pz_ = rz * depth + pd[11];
    bool neg = pz_ <= 0.001f;
    float z = neg ? 1.0f : pz_;
    float zi = __builtin_amdgcn_rcpf(z);
    float px = (neg ? (float)W_ : px_) * zi;
    float py = (neg ? (float)H_ : py_) * zi;
    float x0f = floorf(px), y0f = floorf(py);
    float wx1 = px - x0f, wy1 = py - y0f;
    float wx0 = 1.0f - wx1, wy0 = 1.0f - wy1;
    c0 = 0.0f; c1 = 0.0f; c2 = 0.0f;
    corner(img, x0f,        y0f,        wx0 * wy0, c0, c1, c2);
    corner(img, x0f + 1.0f, y0f,        wx1 * wy0, c0, c1, c2);
    corner(img, x0f,        y0f + 1.0f, wx0 * wy1, c0, c1, c2);
    corner(img, x0f + 1.0f, y0f + 1.0f, wx1 * wy1, c0, c1, c2);
}

__global__ __launch_bounds__(256) void volume_kernel(const float* __restrict__ limg,
                                                     const float* __restrict__ rimg,
                                                     const float* __restrict__ pd,
                                                     float* __restrict__ out) {
    int t = blockIdx.x * 256 + threadIdx.x;
    if (t >= HALF_) return;
    uint32_t bits0 = threefry20_xor(0u, (uint32_t)t);
    uint32_t bits1 = threefry20_xor(0u, (uint32_t)t + (uint32_t)HALF_);
    float n0 = u01(bits0);
    float n1 = u01(bits1);
    int w = t % W_;
    int rest = t / W_;
    int h = rest % H_;
    int d = rest / H_;
    float fd = (float)d;
    float depth0 = __builtin_amdgcn_rcpf(0.025f + ((n0 + fd) * 0.015625f) * 0.075f);
    float depth1 = __builtin_amdgcn_rcpf(0.025f + ((n1 + fd) * 0.015625f) * 0.075f);
    float fx = (float)w;
    float fy = (float)h;
    float l0, l1, l2, r0, r1, r2;
    proj_sample_s(limg, pd + 0, depth0, fx, fy, l0, l1, l2);
    proj_sample_s(rimg, pd + 12, depth0, fx, fy, r0, r1, r2);
    out[t] = fabsf(r0 - l0) + fabsf(r1 - l1) + fabsf(r2 - l2);
    proj_sample_s(limg + 3 * HW_, pd + 24, depth1, fx, fy, l0, l1, l2);
    proj_sample_s(rimg + 3 * HW_, pd + 36, depth1, fx, fy, r0, r1, r2);
    out[t + HALF_] = fabsf(r0 - l0) + fabsf(r1 - l1) + fabsf(r2 - l2);
}

__global__ void setup_only_kernel(const float* __restrict__ lproj, const float* __restrict__ rproj,
                                  const float* __restrict__ gproj, float* __restrict__ pd) {
    int tid = threadIdx.x;
    if (tid >= 4) return;
    int b = tid >> 1;
    int s = tid & 1;
    float inv[16];
    inv4(gproj + b * 16, inv);
    const float* sp = (s == 0 ? lproj : rproj) + b * 16;
    float* o = pd + tid * 12;
    for (int i = 0; i < 3; i++)
        for (int j = 0; j < 3; j++) {
            float acc = 0.0f;
            for (int k = 0; k < 4; k++) acc += sp[i * 4 + k] * inv[k * 4 + j];
            o[i * 3 + j] = acc;
        }
    for (int i = 0; i < 3; i++) {
        float acc = 0.0f;
        for (int k = 0; k < 4; k++) acc += sp[i * 4 + k] * inv[k * 4 + 3];
        o[9 + i] = acc;
    }
}

extern "C" void kernel_launch(void* const* d_in, const int* in_sizes, int n_in,
                              void* d_out, int out_size, void* d_ws, size_t ws_size,
                              hipStream_t stream) {
    const float* limg  = (const float*)d_in[0];
    const float* rimg  = (const float*)d_in[1];
    const float* lproj = (const float*)d_in[2];
    const float* rproj = (const float*)d_in[3];
    const float* gproj = (const float*)d_in[4];
    float* out = (float*)d_out;
    float* pd  = (float*)d_ws;                                  // 52 floats (+flags)
    float4* img4 = (float4*)((char*)d_ws + 256);                // 4*PIMG float4 ~5.8 MB

    const size_t need = 256 + (size_t)4 * PIMG * sizeof(float4);

    if (ws_size >= need) {
        prepass_kernel<<<(4 * PIMG + 255) / 256, 256, 0, stream>>>(limg, rimg, lproj, rproj, gproj, pd, img4);
        volume8_kernel<<<(HALF_ / D_PER + 255) / 256, 256, 0, stream>>>(img4, pd, out);
    } else {
        setup_only_kernel<<<1, 64, 0, stream>>>(lproj, rproj, gproj, pd);
        volume_kernel<<<HALF_ / 256, 256, 0, stream>>>(limg, rimg, pd, out);
    }
}

// Round 7
// 99.839 us; speedup vs baseline: 1.9316x; 1.0007x over previous
//
#include <hip/hip_runtime.h>
#include <stdint.h>

// Problem geometry (fixed by setup_inputs)
#define W_ 320
#define H_ 256
#define HW_ (W_ * H_)
#define NS_ 64
#define B_ 2
#define HALF_ (NS_ * HW_)   // 5,242,880 = NS*H*W
#define D_PER 8
// Padded interleaved layout: per image-row, 16-px zero guard each side
#define PSTRIDE 352
#define POFF 16
#define PIMG (256 * PSTRIDE)   // 90112 float4 per image

// ---------------- 4x4 inverse (Gauss-Jordan, partial pivot) ----------------

__device__ void inv4(const float* m, float* invOut) {
    float a[4][8];
    for (int i = 0; i < 4; i++) {
        for (int j = 0; j < 4; j++) {
            a[i][j] = m[i * 4 + j];
            a[i][j + 4] = (i == j) ? 1.0f : 0.0f;
        }
    }
    for (int c = 0; c < 4; c++) {
        int p = c;
        float best = fabsf(a[c][c]);
        for (int r = c + 1; r < 4; r++) {
            float v = fabsf(a[r][c]);
            if (v > best) { best = v; p = r; }
        }
        if (p != c) {
            for (int j = 0; j < 8; j++) { float tmp = a[c][j]; a[c][j] = a[p][j]; a[p][j] = tmp; }
        }
        float pinv = 1.0f / a[c][c];
        for (int j = 0; j < 8; j++) a[c][j] *= pinv;
        for (int r = 0; r < 4; r++) {
            if (r == c) continue;
            float f = a[r][c];
            for (int j = 0; j < 8; j++) a[r][j] -= f * a[c][j];
        }
    }
    for (int i = 0; i < 4; i++)
        for (int j = 0; j < 4; j++) invOut[i * 4 + j] = a[i][j + 4];
}

// ---------------- fused pre-pass ----------------
// pd: set = b*2+src (src 0=L,1=R): 12 floats {r00..r22,t0,t1,t2}; pd[48+set]=fast flag.
// img4 (padded): img 0=L/b0, 1=L/b1, 2=R/b0, 3=R/b1; element (img,h,xp) at
// img*PIMG + h*PSTRIDE + xp, real x = xp-POFF, zeros outside [0,W).

__global__ __launch_bounds__(256) void prepass_kernel(const float* __restrict__ limg,
                                                      const float* __restrict__ rimg,
                                                      const float* __restrict__ lproj,
                                                      const float* __restrict__ rproj,
                                                      const float* __restrict__ gproj,
                                                      float* __restrict__ pd,
                                                      float4* __restrict__ out4) {
    int p = blockIdx.x * 256 + threadIdx.x;

    if (p < 4) {
        int b = p >> 1;
        int s = p & 1;
        float inv[16];
        inv4(gproj + b * 16, inv);
        const float* sp = (s == 0 ? lproj : rproj) + b * 16;
        float* o = pd + p * 12;
        for (int i = 0; i < 3; i++) {
            for (int j = 0; j < 3; j++) {
                float acc = 0.0f;
                for (int k = 0; k < 4; k++) acc += sp[i * 4 + k] * inv[k * 4 + j];
                o[i * 3 + j] = acc;
            }
        }
        for (int i = 0; i < 3; i++) {
            float acc = 0.0f;
            for (int k = 0; k < 4; k++) acc += sp[i * 4 + k] * inv[k * 4 + 3];
            o[9 + i] = acc;
        }
        // fast iff pure x-shift and |t0| small enough that (a) 8-depth disparity
        // span < 1 px (|t0|*8*0.0011719 < 1) and (b) |disp| <= |t0|*0.1 < POFF-1
        const float eps = 1e-4f;
        bool ok = fabsf(o[0] - 1.0f) < eps && fabsf(o[1]) < eps && fabsf(o[2]) < eps &&
                  fabsf(o[3]) < eps && fabsf(o[4] - 1.0f) < eps && fabsf(o[5]) < eps &&
                  fabsf(o[6]) < eps && fabsf(o[7]) < eps && fabsf(o[8] - 1.0f) < eps &&
                  fabsf(o[10]) < eps && fabsf(o[11]) < eps &&
                  fabsf(o[9]) < 100.0f;
        pd[48 + p] = ok ? 1.0f : 0.0f;
    }

    if (p < 4 * PIMG) {
        int img = p / PIMG;
        int rem = p - img * PIMG;
        int h = rem / PSTRIDE;
        int xp = rem - h * PSTRIDE;
        int x = xp - POFF;
        bool v = (unsigned)x < (unsigned)W_;
        int b = img & 1;
        const float* src = (img < 2 ? limg : rimg) + b * 3 * HW_;
        int pix = h * W_ + min(max(x, 0), W_ - 1);
        float4 val;
        val.x = v ? src[pix] : 0.0f;
        val.y = v ? src[HW_ + pix] : 0.0f;
        val.z = v ? src[2 * HW_ + pix] : 0.0f;
        val.w = 0.0f;
        out4[p] = val;
    }
}

// ---------------- RNG ----------------

__device__ __forceinline__ float u01(uint32_t b) {
    b = (b >> 9) | 0x3F800000u;
    return __uint_as_float(b) - 1.0f;
}

#define TF_ROUND(r) { x0 += x1; x1 = (x1 << (r)) | (x1 >> (32 - (r))); x1 ^= x0; }

// Threefry-2x32-20, key=(0,1), partitionable-JAX finalizer (out0 ^ out1)
__device__ __forceinline__ uint32_t threefry20_xor(uint32_t c0, uint32_t c1) {
    const uint32_t ks0 = 0u, ks1 = 1u, ks2 = 0x1BD11BDAu ^ ks0 ^ ks1;
    uint32_t x0 = c0 + ks0;
    uint32_t x1 = c1 + ks1;
    TF_ROUND(13) TF_ROUND(15) TF_ROUND(26) TF_ROUND(6)
    x0 += ks1; x1 += ks2 + 1u;
    TF_ROUND(17) TF_ROUND(29) TF_ROUND(16) TF_ROUND(24)
    x0 += ks2; x1 += ks0 + 2u;
    TF_ROUND(13) TF_ROUND(15) TF_ROUND(26) TF_ROUND(6)
    x0 += ks0; x1 += ks1 + 3u;
    TF_ROUND(17) TF_ROUND(29) TF_ROUND(16) TF_ROUND(24)
    x0 += ks1; x1 += ks2 + 4u;
    TF_ROUND(13) TF_ROUND(15) TF_ROUND(26) TF_ROUND(6)
    x0 += ks2; x1 += ks0 + 5u;
    return x0 ^ x1;
}

__device__ __forceinline__ float noise_den(uint32_t t, float fd) {
    return 0.025f + (u01(threefry20_xor(0u, t)) + fd) * 0.001171875f;
}

// ---------------- helpers ----------------

struct F3 { float x, y, z; };

__device__ __forceinline__ float adiff3(F3 a, F3 b) {
    return fabsf(a.x - b.x) + fabsf(a.y - b.y) + fabsf(a.z - b.z);
}

// hat-weight 3-tap lerp: x in [0,2), taps at offsets 0,1,2 from floor base
__device__ __forceinline__ F3 hat3(float4 q0, float4 q1, float4 q2, float x) {
    float t = x - 1.0f;
    float w0 = fmaxf(0.0f, 1.0f - x);
    float w1 = 1.0f - fabsf(t);
    float w2 = fmaxf(0.0f, t);
    F3 o;
    o.x = q0.x * w0 + q1.x * w1 + q2.x * w2;
    o.y = q0.y * w0 + q1.y * w1 + q2.y * w2;
    o.z = q0.z * w0 + q1.z * w1 + q2.z * w2;
    return o;
}

// full 2-D bilinear on padded layout (general path)
__device__ __forceinline__ F3 bil4(const float4* __restrict__ img, float px, float py) {
    float x0f = floorf(px), y0f = floorf(py);
    float wx1 = px - x0f, wy1 = py - y0f;
    float wx0 = 1.0f - wx1, wy0 = 1.0f - wy1;
    int xi = (int)x0f, yi = (int)y0f;
    bool vx0 = (unsigned)xi < (unsigned)W_;
    bool vx1 = (unsigned)(xi + 1) < (unsigned)W_;
    bool vy0 = (unsigned)yi < (unsigned)H_;
    bool vy1 = (unsigned)(yi + 1) < (unsigned)H_;
    int cx0 = min(max(xi, 0), W_ - 1) + POFF;
    int cx1 = min(max(xi + 1, 0), W_ - 1) + POFF;
    int r0 = min(max(yi, 0), H_ - 1) * PSTRIDE;
    int r1 = min(max(yi + 1, 0), H_ - 1) * PSTRIDE;
    float w00 = (vx0 && vy0) ? wx0 * wy0 : 0.0f;
    float w10 = (vx1 && vy0) ? wx1 * wy0 : 0.0f;
    float w01 = (vx0 && vy1) ? wx0 * wy1 : 0.0f;
    float w11 = (vx1 && vy1) ? wx1 * wy1 : 0.0f;
    float4 p00 = img[r0 + cx0];
    float4 p10 = img[r0 + cx1];
    float4 p01 = img[r1 + cx0];
    float4 p11 = img[r1 + cx1];
    F3 o;
    o.x = p00.x * w00 + p10.x * w10 + p01.x * w01 + p11.x * w11;
    o.y = p00.y * w00 + p10.y * w10 + p01.y * w01 + p11.y * w11;
    o.z = p00.z * w00 + p10.z * w10 + p01.z * w01 + p11.z * w11;
    return o;
}

__device__ __forceinline__ F3 proj_bil(const float4* __restrict__ img,
                                       float rx, float ry, float rz,
                                       float tx, float ty, float tz, float depth) {
    float px_ = rx * depth + tx;
    float py_ = ry * depth + ty;
    float pz_ = rz * depth + tz;
    bool neg = pz_ <= 0.001f;
    float z = neg ? 1.0f : pz_;
    float zi = __builtin_amdgcn_rcpf(z);
    float px = (neg ? (float)W_ : px_) * zi;
    float py = (neg ? (float)H_ : py_) * zi;
    return bil4(img, px, py);
}

// ---------------- FAST kernel: pure x-shift specialization, early-exit otherwise ----
// Separate kernel so the fat general path cannot inflate this kernel's VGPR
// allocation (register-pressure contamination theory, R6 post-mortem).

__global__ __launch_bounds__(256) void volume8_fast(const float4* __restrict__ img4,
                                                    const float* __restrict__ pd,
                                                    float* __restrict__ out) {
    // wave-uniform flag; if not fast, the general kernel handles everything
    if (!((pd[48] != 0.0f) & (pd[49] != 0.0f) & (pd[50] != 0.0f) & (pd[51] != 0.0f)))
        return;

    int u = blockIdx.x * 256 + threadIdx.x;
    if (u >= HALF_ / D_PER) return;
    int pix = u % HW_;
    int dgrp = u / HW_;
    int w = pix % W_;
    int h = pix / W_;
    int d0 = dgrp * D_PER;
    int tbase = d0 * HW_ + pix;

    const float4* rowL0 = img4 + 0 * PIMG + h * PSTRIDE + POFF + w;
    const float4* rowL1 = img4 + 1 * PIMG + h * PSTRIDE + POFF + w;
    const float4* rowR0 = img4 + 2 * PIMG + h * PSTRIDE + POFF + w;
    const float4* rowR1 = img4 + 3 * PIMG + h * PSTRIDE + POFF + w;

    float tl0 = pd[0 * 12 + 9];
    float tr0 = pd[1 * 12 + 9];
    float tl1 = pd[2 * 12 + 9];
    float tr1 = pd[3 * 12 + 9];

    float den0[D_PER], den1[D_PER];
    // Stage A: extreme-j noise to place taps (den strictly increasing in j)
    den0[0]         = noise_den((uint32_t)tbase,                               (float)d0);
    den0[D_PER - 1] = noise_den((uint32_t)(tbase + (D_PER - 1) * HW_),         (float)(d0 + D_PER - 1));
    den1[0]         = noise_den((uint32_t)(tbase + HALF_),                     (float)d0);
    den1[D_PER - 1] = noise_den((uint32_t)(tbase + (D_PER - 1) * HW_ + HALF_), (float)(d0 + D_PER - 1));

    // Stage B: tap bases + issue all 12 loads
    float dmL0 = (tl0 >= 0.0f) ? den0[0] : den0[D_PER - 1];
    float dmR0 = (tr0 >= 0.0f) ? den0[0] : den0[D_PER - 1];
    float dmL1 = (tl1 >= 0.0f) ? den1[0] : den1[D_PER - 1];
    float dmR1 = (tr1 >= 0.0f) ? den1[0] : den1[D_PER - 1];
    float fmL0 = floorf(tl0 * dmL0);
    float fmR0 = floorf(tr0 * dmR0);
    float fmL1 = floorf(tl1 * dmL1);
    float fmR1 = floorf(tr1 * dmR1);
    const float4* tL0 = rowL0 + (int)fmL0;
    const float4* tR0 = rowR0 + (int)fmR0;
    const float4* tL1 = rowL1 + (int)fmL1;
    const float4* tR1 = rowR1 + (int)fmR1;
    float4 qL0a = tL0[0], qL0b = tL0[1], qL0c = tL0[2];
    float4 qR0a = tR0[0], qR0b = tR0[1], qR0c = tR0[2];
    float4 qL1a = tL1[0], qL1b = tL1[1], qL1c = tL1[2];
    float4 qR1a = tR1[0], qR1b = tR1[1], qR1c = tR1[2];

    // Stage C: remaining threefry in the load shadow
#pragma unroll
    for (int j = 1; j < D_PER - 1; j++) {
        den0[j] = noise_den((uint32_t)(tbase + j * HW_),         (float)(d0 + j));
        den1[j] = noise_den((uint32_t)(tbase + j * HW_ + HALF_), (float)(d0 + j));
    }

    // Stage D: lerp + diff + store
#pragma unroll
    for (int j = 0; j < D_PER; j++) {
        F3 l0 = hat3(qL0a, qL0b, qL0c, tl0 * den0[j] - fmL0);
        F3 r0 = hat3(qR0a, qR0b, qR0c, tr0 * den0[j] - fmR0);
        out[tbase + j * HW_] = adiff3(r0, l0);
        F3 l1 = hat3(qL1a, qL1b, qL1c, tl1 * den1[j] - fmL1);
        F3 r1 = hat3(qR1a, qR1b, qR1c, tr1 * den1[j] - fmR1);
        out[tbase + j * HW_ + HALF_] = adiff3(r1, l1);
    }
}

// ---------------- GENERAL kernel: early-exit if the fast kernel handled it ----

__global__ __launch_bounds__(256) void volume8_general(const float4* __restrict__ img4,
                                                       const float* __restrict__ pd,
                                                       float* __restrict__ out) {
    if ((pd[48] != 0.0f) & (pd[49] != 0.0f) & (pd[50] != 0.0f) & (pd[51] != 0.0f))
        return;

    int u = blockIdx.x * 256 + threadIdx.x;
    if (u >= HALF_ / D_PER) return;
    int pix = u % HW_;
    int dgrp = u / HW_;
    int w = pix % W_;
    int h = pix / W_;
    int d0 = dgrp * D_PER;
    int tbase = d0 * HW_ + pix;

    float fx = (float)w;
    float fy = (float)h;
    float rx[4], ry[4], rz[4], tx[4], ty[4], tz[4];
#pragma unroll
    for (int s = 0; s < 4; s++) {
        const float* q = pd + s * 12;
        rx[s] = q[0] * fx + q[1] * fy + q[2];
        ry[s] = q[3] * fx + q[4] * fy + q[5];
        rz[s] = q[6] * fx + q[7] * fy + q[8];
        tx[s] = q[9]; ty[s] = q[10]; tz[s] = q[11];
    }
    const float4* I0 = img4;
    const float4* I1 = img4 + PIMG;
    const float4* I2 = img4 + 2 * PIMG;
    const float4* I3 = img4 + 3 * PIMG;
#pragma unroll 2
    for (int j = 0; j < D_PER; j++) {
        int d = d0 + j;
        int t = tbase + j * HW_;
        uint32_t bits0 = threefry20_xor(0u, (uint32_t)t);
        uint32_t bits1 = threefry20_xor(0u, (uint32_t)(t + HALF_));
        float fd = (float)d;
        float depth0 = __builtin_amdgcn_rcpf(0.025f + (u01(bits0) + fd) * 0.001171875f);
        float depth1 = __builtin_amdgcn_rcpf(0.025f + (u01(bits1) + fd) * 0.001171875f);

        F3 l0 = proj_bil(I0, rx[0], ry[0], rz[0], tx[0], ty[0], tz[0], depth0);
        F3 r0 = proj_bil(I2, rx[1], ry[1], rz[1], tx[1], ty[1], tz[1], depth0);
        F3 l1 = proj_bil(I1, rx[2], ry[2], rz[2], tx[2], ty[2], tz[2], depth1);
        F3 r1 = proj_bil(I3, rx[3], ry[3], rz[3], tx[3], ty[3], tz[3], depth1);

        out[t] = adiff3(r0, l0);
        out[t + HALF_] = adiff3(r1, l1);
    }
}

// ---------------- fallback (no-workspace path, round-2 proven) ----------------

__device__ __forceinline__ void corner(const float* __restrict__ img, float xc, float yc, float wgt,
                                       float& c0, float& c1, float& c2) {
    bool valid = (xc >= 0.0f) & (xc <= (float)(W_ - 1)) & (yc >= 0.0f) & (yc <= (float)(H_ - 1));
    float xcc = fminf(fmaxf(xc, 0.0f), (float)(W_ - 1));
    float ycc = fminf(fmaxf(yc, 0.0f), (float)(H_ - 1));
    int xi = (int)xcc;
    int yi = (int)ycc;
    int off = yi * W_ + xi;
    float wv = valid ? wgt : 0.0f;
    c0 += img[off] * wv;
    c1 += img[HW_ + off] * wv;
    c2 += img[2 * HW_ + off] * wv;
}

__device__ __forceinline__ void proj_sample_s(const float* __restrict__ img, const float* __restrict__ pd,
                                              float depth, float x, float y,
                                              float& c0, float& c1, float& c2) {
    float rx = pd[0] * x + pd[1] * y + pd[2];
    float ry = pd[3] * x + pd[4] * y + pd[5];
    float rz = pd[6] * x + pd[7] * y + pd[8];
    float px_ = rx * depth + pd[9];
    float py_ = ry * depth + pd[10];
    float pz_ = rz * depth + pd[11];
    bool neg = pz_ <= 0.001f;
    float z = neg ? 1.0f : pz_;
    float zi = __builtin_amdgcn_rcpf(z);
    float px = (neg ? (float)W_ : px_) * zi;
    float py = (neg ? (float)H_ : py_) * zi;
    float x0f = floorf(px), y0f = floorf(py);
    float wx1 = px - x0f, wy1 = py - y0f;
    float wx0 = 1.0f - wx1, wy0 = 1.0f - wy1;
    c0 = 0.0f; c1 = 0.0f; c2 = 0.0f;
    corner(img, x0f,        y0f,        wx0 * wy0, c0, c1, c2);
    corner(img, x0f + 1.0f, y0f,        wx1 * wy0, c0, c1, c2);
    corner(img, x0f,        y0f + 1.0f, wx0 * wy1, c0, c1, c2);
    corner(img, x0f + 1.0f, y0f + 1.0f, wx1 * wy1, c0, c1, c2);
}

__global__ __launch_bounds__(256) void volume_kernel(const float* __restrict__ limg,
                                                     const float* __restrict__ rimg,
                                                     const float* __restrict__ pd,
                                                     float* __restrict__ out) {
    int t = blockIdx.x * 256 + threadIdx.x;
    if (t >= HALF_) return;
    uint32_t bits0 = threefry20_xor(0u, (uint32_t)t);
    uint32_t bits1 = threefry20_xor(0u, (uint32_t)t + (uint32_t)HALF_);
    float n0 = u01(bits0);
    float n1 = u01(bits1);
    int w = t % W_;
    int rest = t / W_;
    int h = rest % H_;
    int d = rest / H_;
    float fd = (float)d;
    float depth0 = __builtin_amdgcn_rcpf(0.025f + ((n0 + fd) * 0.015625f) * 0.075f);
    float depth1 = __builtin_amdgcn_rcpf(0.025f + ((n1 + fd) * 0.015625f) * 0.075f);
    float fx = (float)w;
    float fy = (float)h;
    float l0, l1, l2, r0, r1, r2;
    proj_sample_s(limg, pd + 0, depth0, fx, fy, l0, l1, l2);
    proj_sample_s(rimg, pd + 12, depth0, fx, fy, r0, r1, r2);
    out[t] = fabsf(r0 - l0) + fabsf(r1 - l1) + fabsf(r2 - l2);
    proj_sample_s(limg + 3 * HW_, pd + 24, depth1, fx, fy, l0, l1, l2);
    proj_sample_s(rimg + 3 * HW_, pd + 36, depth1, fx, fy, r0, r1, r2);
    out[t + HALF_] = fabsf(r0 - l0) + fabsf(r1 - l1) + fabsf(r2 - l2);
}

__global__ void setup_only_kernel(const float* __restrict__ lproj, const float* __restrict__ rproj,
                                  const float* __restrict__ gproj, float* __restrict__ pd) {
    int tid = threadIdx.x;
    if (tid >= 4) return;
    int b = tid >> 1;
    int s = tid & 1;
    float inv[16];
    inv4(gproj + b * 16, inv);
    const float* sp = (s == 0 ? lproj : rproj) + b * 16;
    float* o = pd + tid * 12;
    for (int i = 0; i < 3; i++)
        for (int j = 0; j < 3; j++) {
            float acc = 0.0f;
            for (int k = 0; k < 4; k++) acc += sp[i * 4 + k] * inv[k * 4 + j];
            o[i * 3 + j] = acc;
        }
    for (int i = 0; i < 3; i++) {
        float acc = 0.0f;
        for (int k = 0; k < 4; k++) acc += sp[i * 4 + k] * inv[k * 4 + 3];
        o[9 + i] = acc;
    }
}

extern "C" void kernel_launch(void* const* d_in, const int* in_sizes, int n_in,
                              void* d_out, int out_size, void* d_ws, size_t ws_size,
                              hipStream_t stream) {
    const float* limg  = (const float*)d_in[0];
    const float* rimg  = (const float*)d_in[1];
    const float* lproj = (const float*)d_in[2];
    const float* rproj = (const float*)d_in[3];
    const float* gproj = (const float*)d_in[4];
    float* out = (float*)d_out;
    float* pd  = (float*)d_ws;                                  // 52 floats (+flags)
    float4* img4 = (float4*)((char*)d_ws + 256);                // 4*PIMG float4 ~5.8 MB

    const size_t need = 256 + (size_t)4 * PIMG * sizeof(float4);

    if (ws_size >= need) {
        prepass_kernel<<<(4 * PIMG + 255) / 256, 256, 0, stream>>>(limg, rimg, lproj, rproj, gproj, pd, img4);
        int grid = (HALF_ / D_PER + 255) / 256;
        volume8_fast<<<grid, 256, 0, stream>>>(img4, pd, out);
        volume8_general<<<grid, 256, 0, stream>>>(img4, pd, out);
    } else {
        setup_only_kernel<<<1, 64, 0, stream>>>(lproj, rproj, gproj, pd);
        volume_kernel<<<HALF_ / 256, 256, 0, stream>>>(limg, rimg, pd, out);
    }
}